// Round 1
// baseline (945.056 us; speedup 1.0000x reference)
//
#include <hip/hip_runtime.h>
#include <hip/hip_bf16.h>
#include <cstdint>
#include <cstddef>

// ---------- types ----------
typedef __attribute__((ext_vector_type(8))) short    bf16x8;   // 8 bf16 = 4 VGPRs (MFMA A/B frag)
typedef __attribute__((ext_vector_type(4))) float    f32x4;    // MFMA C/D frag
typedef __attribute__((ext_vector_type(8))) unsigned short u16x8;
typedef __attribute__((ext_vector_type(4))) float    f32v4;
typedef __attribute__((ext_vector_type(4))) unsigned short u16v4;

__device__ __forceinline__ float b2f(unsigned short v) {
    return __builtin_bit_cast(float, ((unsigned int)v) << 16);
}
__device__ __forceinline__ unsigned short f2b(float f) {
    unsigned int u = __builtin_bit_cast(unsigned int, f);
    u += 0x7fffu + ((u >> 16) & 1u);        // RNE
    return (unsigned short)(u >> 16);
}

__device__ __forceinline__ void async16(const void* g, void* l) {
    __builtin_amdgcn_global_load_lds(
        (const __attribute__((address_space(1))) unsigned int*)g,
        (__attribute__((address_space(3))) unsigned int*)l, 16, 0, 0);
}

// ---------- f32 -> bf16 convert ----------
__global__ __launch_bounds__(256) void cvt_f32_bf16(const float* __restrict__ src,
                                                    unsigned short* __restrict__ dst, int n4) {
    int i = blockIdx.x * blockDim.x + threadIdx.x;
    int stride = gridDim.x * blockDim.x;
    const f32v4* s4 = (const f32v4*)src;
    u16v4* d4 = (u16v4*)dst;
    for (; i < n4; i += stride) {
        f32v4 v = s4[i];
        u16v4 o;
        o.x = f2b(v.x); o.y = f2b(v.y); o.z = f2b(v.z); o.w = f2b(v.w);
        d4[i] = o;
    }
}

// ---------- bf16 MFMA GEMM: C[m][n] = sum_k A[m][k]*Bw[n][k] + bias[n] ----------
// MODE 0: Cout = float, row-major [M][N]
// MODE 1: Cout = bf16, "u layout": Cout[(b*CH + n)*Lseq + l], m = b*Lseq + l (tile never straddles b)
template <int MODE>
__global__ __launch_bounds__(256, 2) void gemm_bf16(
    const unsigned short* __restrict__ A,   // M x K bf16 row-major
    const unsigned short* __restrict__ Bw,  // N x K bf16 row-major
    const float* __restrict__ bias,         // N
    void* __restrict__ Cout,
    int M, int N, int K, int Lseq, int CH)
{
    constexpr int SMEM_N = (MODE == 1) ? 16384 : 8192;
    __shared__ unsigned short smem[SMEM_N];  // A tile [128][32] @0, B tile [128][32] @4096 (ushort idx)

    const int tid  = threadIdx.x;
    const int w    = tid >> 6;
    const int lane = tid & 63;
    const int quad = lane >> 4;
    const int lq   = lane & 15;
    const int n0 = blockIdx.x * 128;
    const int m0 = blockIdx.y * 128;
    const int wave_m = w & 1, wave_n = w >> 1;

    // staging: each wave copies 2KB of A + 2KB of B per K-step, 16B/lane/inst
    const int rSub = w * 32 + (lane >> 2);
    const int kcol = (lane & 3) * 8;
    const unsigned short* pA0 = A  + (size_t)(m0 + rSub)      * K + kcol;
    const unsigned short* pA1 = A  + (size_t)(m0 + rSub + 16) * K + kcol;
    const unsigned short* pB0 = Bw + (size_t)(n0 + rSub)      * K + kcol;
    const unsigned short* pB1 = Bw + (size_t)(n0 + rSub + 16) * K + kcol;
    char* sb = (char*)smem;
    char* dA0 = sb + w * 2048;
    char* dA1 = sb + w * 2048 + 1024;
    char* dB0 = sb + 8192 + w * 2048;
    char* dB1 = sb + 8192 + w * 2048 + 1024;

    f32x4 acc[4][4] = {};

    const int nIter = K >> 5;
    for (int kt = 0; kt < nIter; ++kt) {
        async16(pA0, dA0); async16(pA1, dA1);
        async16(pB0, dB0); async16(pB1, dB1);
        pA0 += 32; pA1 += 32; pB0 += 32; pB1 += 32;
        __syncthreads();   // drains vmcnt before LDS reads
        bf16x8 af[4], bw[4];
        #pragma unroll
        for (int i = 0; i < 4; ++i) {
            af[i] = *(const bf16x8*)&smem[(wave_m * 64 + i * 16 + lq) * 32 + quad * 8];
            bw[i] = *(const bf16x8*)&smem[4096 + (wave_n * 64 + i * 16 + lq) * 32 + quad * 8];
        }
        #pragma unroll
        for (int i = 0; i < 4; ++i)
            #pragma unroll
            for (int j = 0; j < 4; ++j)
                acc[i][j] = __builtin_amdgcn_mfma_f32_16x16x32_bf16(af[i], bw[j], acc[i][j], 0, 0, 0);
        __syncthreads();   // protect smem before next staging
    }

    if (MODE == 0) {
        float* out = (float*)Cout;
        #pragma unroll
        for (int j = 0; j < 4; ++j) {
            const int col = n0 + wave_n * 64 + j * 16 + lq;
            const float bv = bias[col];
            #pragma unroll
            for (int i = 0; i < 4; ++i) {
                const int rowb = m0 + wave_m * 64 + i * 16 + quad * 4;
                f32x4 c = acc[i][j];
                out[(size_t)(rowb + 0) * N + col] = c.x + bv;
                out[(size_t)(rowb + 1) * N + col] = c.y + bv;
                out[(size_t)(rowb + 2) * N + col] = c.z + bv;
                out[(size_t)(rowb + 3) * N + col] = c.w + bv;
            }
        }
    } else {
        // transpose through LDS so output rows (fixed channel, contiguous l) store coalesced
        #pragma unroll
        for (int j = 0; j < 4; ++j) {
            const int nl = wave_n * 64 + j * 16 + lq;
            const float bv = bias[n0 + nl];
            #pragma unroll
            for (int i = 0; i < 4; ++i) {
                const int ml = wave_m * 64 + i * 16 + quad * 4;
                f32x4 c = acc[i][j];
                smem[nl * 128 + ml + 0] = f2b(c.x + bv);
                smem[nl * 128 + ml + 1] = f2b(c.y + bv);
                smem[nl * 128 + ml + 2] = f2b(c.z + bv);
                smem[nl * 128 + ml + 3] = f2b(c.w + bv);
            }
        }
        __syncthreads();
        unsigned short* uo = (unsigned short*)Cout;
        const int bI = m0 >> 12;        // 4096 rows per batch
        const int l0 = m0 & 4095;
        // full 128x128 tile: 2048 chunks of 8 ushorts (16B/lane, coalesced)
        for (int e = tid; e < 2048; e += 256) {
            const int nl = e >> 4, seg = e & 15;
            u16x8 v = *(const u16x8*)&smem[nl * 128 + seg * 8];
            *(u16x8*)&uo[(size_t)(bI * CH + n0 + nl) * Lseq + l0 + seg * 8] = v;
        }
    }
}

// ---------- Hyena filter k(D,L) ----------
__global__ __launch_bounds__(256) void filter_kernel(
    const float* __restrict__ w0, const float* __restrict__ b0,
    const float* __restrict__ freq,
    const float* __restrict__ w1, const float* __restrict__ b1,
    const float* __restrict__ w2, const float* __restrict__ b2,
    const float* __restrict__ w3, float* __restrict__ kf)
{
    __shared__ float ha[64][64];
    __shared__ float hb[64][64];
    const int tid = threadIdx.x;
    const int l0 = blockIdx.x * 64;
    const int d0 = blockIdx.y * 256;
    const int l  = tid & 63;
    const int lg = l0 + l;
    const float tt = (float)lg * (1.0f / 4095.0f);
    const float wang = 6.283185307179586f * (float)lg * (1.0f / 4096.0f);
    const float a  = 1e-4f * wang;
    const float z0 = tt, z1 = cosf(a), z2 = -sinf(a);

    for (int e = tid; e < 4096; e += 256) {
        const int dim = e >> 6;
        float pre = z0 * w0[dim * 3] + z1 * w0[dim * 3 + 1] + z2 * w0[dim * 3 + 2] + b0[dim];
        ha[dim][l] = sinf(freq[dim] * pre);
    }
    __syncthreads();
    for (int e = tid; e < 4096; e += 256) {
        const int dim = e >> 6;
        float acc = b1[dim];
        #pragma unroll
        for (int jj = 0; jj < 64; ++jj) acc += w1[dim * 64 + jj] * ha[jj][l];
        hb[dim][l] = sinf(freq[dim] * acc);
    }
    __syncthreads();
    for (int e = tid; e < 4096; e += 256) {
        const int dim = e >> 6;
        float acc = b2[dim];
        #pragma unroll
        for (int jj = 0; jj < 64; ++jj) acc += w2[dim * 64 + jj] * hb[jj][l];
        ha[dim][l] = sinf(freq[dim] * acc);
    }
    __syncthreads();
    for (int d = d0 + (tid >> 6); d < d0 + 256; d += 4) {
        float acc = 0.f;
        #pragma unroll
        for (int jj = 0; jj < 64; ++jj) acc += w3[d * 64 + jj] * ha[jj][l];
        // deltas = linspace(ln(.01)/1.5, ln(.01)/0.3, 2048); decay = exp(-t*|delta|)
        const float delta = fabsf(-3.0701134573253944f + (-5.999245642062483e-3f) * (float)d);
        kf[(size_t)d * 4096 + lg] = acc * __expf(-tt * delta);
    }
}

// ================= register-resident 8192-pt FFT (512 thr, 16 pts/thr) =================
// Ownerships: A: p = t + 512 s | B: p = (t>>5)*512 + (t&31) + 32 s | C: p = 16 t + j
// DIF forward ends bit-reversed-contiguous (C); inverse DIT consumes C and ends at A.
// LDS padded idx + (idx>>5): all three access patterns are <=2-way (free) bank aliasing.
#define PIDX(i) ((i) + ((i) >> 5))

__device__ __forceinline__ void bfly_f(float& r1, float& i1, float& r2, float& i2, float wr, float wi) {
    float ur = r1, ui = i1, vr = r2, vi = i2;
    r1 = ur + vr; i1 = ui + vi;
    float dr = ur - vr, di = ui - vi;
    r2 = dr * wr - di * wi;
    i2 = dr * wi + di * wr;
}
__device__ __forceinline__ void bfly_i(float& r1, float& i1, float& r2, float& i2, float wr, float wi) {
    float vr = r2 * wr - i2 * wi, vi = r2 * wi + i2 * wr;
    float ur = r1, ui = i1;
    r1 = ur + vr; i1 = ui + vi;
    r2 = ur - vr; i2 = ui - vi;
}

// stage hm = STR*DS; j = tt + STR*(s mod DS); theta = -pi*j/hm (fwd) / +pi*j/hm (inv)
template <int DS, int STR>
__device__ __forceinline__ void fwd_stage(float* re, float* im, int tt) {
    float wr[8], wi[8];
    constexpr float c = -3.14159265358979f / (float)(STR * DS);
    #pragma unroll
    for (int k = 0; k < DS; ++k) __sincosf(c * (float)(tt + STR * k), &wi[k], &wr[k]);
    #pragma unroll
    for (int s = 0; s < 16; ++s)
        if ((s & DS) == 0)
            bfly_f(re[s], im[s], re[s + DS], im[s + DS], wr[s & (DS - 1)], wi[s & (DS - 1)]);
}
template <int DS, int STR>
__device__ __forceinline__ void inv_stage(float* re, float* im, int tt) {
    float wr[8], wi[8];
    constexpr float c = 3.14159265358979f / (float)(STR * DS);
    #pragma unroll
    for (int k = 0; k < DS; ++k) __sincosf(c * (float)(tt + STR * k), &wi[k], &wr[k]);
    #pragma unroll
    for (int s = 0; s < 16; ++s)
        if ((s & DS) == 0)
            bfly_i(re[s], im[s], re[s + DS], im[s + DS], wr[s & (DS - 1)], wi[s & (DS - 1)]);
}

__device__ __forceinline__ void xchg(float* re, float* im, float* fre, float* fim,
                                     int wbase, int wstr, int rbase, int rstr) {
    __syncthreads();           // protect prior reads of fre/fim
    #pragma unroll
    for (int s = 0; s < 16; ++s) {
        const int i = wbase + wstr * s;
        fre[PIDX(i)] = re[s]; fim[PIDX(i)] = im[s];
    }
    __syncthreads();
    #pragma unroll
    for (int s = 0; s < 16; ++s) {
        const int i = rbase + rstr * s;
        re[s] = fre[PIDX(i)]; im[s] = fim[PIDX(i)];
    }
}

__device__ __forceinline__ void fwd_fft(float* re, float* im, float* fre, float* fim, int t) {
    const int off = t & 31, seg = t >> 5;
    fwd_stage<8, 512>(re, im, t);
    fwd_stage<4, 512>(re, im, t);
    fwd_stage<2, 512>(re, im, t);
    fwd_stage<1, 512>(re, im, t);
    xchg(re, im, fre, fim, t, 512, seg * 512 + off, 32);        // A -> B
    fwd_stage<8, 32>(re, im, off);
    fwd_stage<4, 32>(re, im, off);
    fwd_stage<2, 32>(re, im, off);
    fwd_stage<1, 32>(re, im, off);
    {   // hm = 16 (m = 32) across threads t ^ 16; j = off & 15 (thread-constant)
        float wr, wi;
        __sincosf(-3.14159265358979f * (float)(off & 15) / 16.0f, &wi, &wr);
        const bool hi = (off & 16) != 0;
        #pragma unroll
        for (int s = 0; s < 16; ++s) {
            float rr = __shfl_xor(re[s], 16);
            float ri = __shfl_xor(im[s], 16);
            if (!hi) { re[s] += rr; im[s] += ri; }
            else {
                float dr = rr - re[s], di = ri - im[s];
                re[s] = dr * wr - di * wi;
                im[s] = dr * wi + di * wr;
            }
        }
    }
    xchg(re, im, fre, fim, seg * 512 + off, 32, 16 * t, 1);     // B -> C
    fwd_stage<8, 1>(re, im, 0);
    fwd_stage<4, 1>(re, im, 0);
    fwd_stage<2, 1>(re, im, 0);
    fwd_stage<1, 1>(re, im, 0);
}

__device__ __forceinline__ void inv_fft(float* re, float* im, float* fre, float* fim, int t) {
    const int off = t & 31, seg = t >> 5;
    inv_stage<1, 1>(re, im, 0);
    inv_stage<2, 1>(re, im, 0);
    inv_stage<4, 1>(re, im, 0);
    inv_stage<8, 1>(re, im, 0);
    xchg(re, im, fre, fim, 16 * t, 1, seg * 512 + off, 32);     // C -> B
    {   // hm = 16 (m = 32), conj twiddle; v' = W * x[p+16]
        float wr, wi;
        __sincosf(3.14159265358979f * (float)(off & 15) / 16.0f, &wi, &wr);
        const bool hi = (off & 16) != 0;
        #pragma unroll
        for (int s = 0; s < 16; ++s) {
            float rr = __shfl_xor(re[s], 16);
            float ri = __shfl_xor(im[s], 16);
            if (!hi) {           // u = own, v' = W * recv
                float vr = rr * wr - ri * wi, vi = rr * wi + ri * wr;
                re[s] += vr; im[s] += vi;
            } else {             // u = recv, v' = W * own
                float vr = re[s] * wr - im[s] * wi, vi = re[s] * wi + im[s] * wr;
                re[s] = rr - vr; im[s] = ri - vi;
            }
        }
    }
    inv_stage<1, 32>(re, im, off);
    inv_stage<2, 32>(re, im, off);
    inv_stage<4, 32>(re, im, off);
    inv_stage<8, 32>(re, im, off);
    xchg(re, im, fre, fim, seg * 512 + off, 32, t, 512);        // B -> A
    inv_stage<1, 512>(re, im, t);
    inv_stage<2, 512>(re, im, t);
    inv_stage<4, 512>(re, im, t);
    inv_stage<8, 512>(re, im, t);
}

// ---------- K-spectrum precompute: kspec[d] = FFT_8192(zero-padded k_d) ----------
// Layout: q-major f32x4 per (d, q, t): kspec4[d*4096 + q*512 + t] = {Kr[16t+2q], Ki[16t+2q],
// Kr[16t+2q+1], Ki[16t+2q+1]} (C ownership) -> per-instruction lane-contiguous on both sides.
__global__ __launch_bounds__(512, 4) void kfft_kernel(
    const float* __restrict__ kf,   // (D, L) f32
    float* __restrict__ kspec)      // (D, 8192) complex, packed as above
{
    __shared__ float fre[8448];
    __shared__ float fim[8448];
    const int t = threadIdx.x;
    const int d = blockIdx.x;
    float kr[16], ki[16];
    #pragma unroll
    for (int s = 0; s < 16; ++s) {
        kr[s] = (s < 8) ? kf[(size_t)d * 4096 + t + 512 * s] : 0.f;
        ki[s] = 0.f;
    }
    fwd_fft(kr, ki, fre, fim, t);
    f32x4* kv = (f32x4*)kspec + (size_t)d * 4096 + t;
    #pragma unroll
    for (int q = 0; q < 8; ++q) {
        f32x4 o;
        o.x = kr[2 * q]; o.y = ki[2 * q];
        o.z = kr[2 * q + 1]; o.w = ki[2 * q + 1];
        kv[q * 512] = o;
    }
}

// ---------- fused: short conv + gate + fftconv + bias + x0 gate -> zb (B,D,L) bf16 ----------
// LDS = fre/fim only (67,584 B) -> 2 blocks/CU; K spectrum streamed from global.
__global__ __launch_bounds__(512, 4) void hyena_fft_kernel(
    const unsigned short* __restrict__ u,   // (B, 3D, L) bf16
    const float* __restrict__ kspec,        // (D, 8192) complex, q-major f32x4
    const float* __restrict__ sw,           // (3D, 1, 3)
    const float* __restrict__ sbv,          // (3D)
    const float* __restrict__ fbias,        // (D)
    unsigned short* __restrict__ zb)        // (B, D, L) bf16
{
    __shared__ float fre[8448];
    __shared__ float fim[8448];
    const int t = threadIdx.x;
    const int d = blockIdx.x;

    // ---- phase 1: short conv (causal taps w0*u[l-2]+w1*u[l-1]+w2*u[l]) + gating, A ownership ----
    const int c0 = d, c1 = 2048 + d, c2 = 4096 + d;
    const float w00 = sw[c0*3+0], w01 = sw[c0*3+1], w02 = sw[c0*3+2], bb0 = sbv[c0];
    const float w10 = sw[c1*3+0], w11 = sw[c1*3+1], w12 = sw[c1*3+2], bb1 = sbv[c1];
    const float w20 = sw[c2*3+0], w21 = sw[c2*3+1], w22 = sw[c2*3+2], bb2 = sbv[c2];
    const float fb = fbias[d];

    float vgr_[2][8], x0r_[2][8];
    float xr[16], xi[16];
    #pragma unroll
    for (int s = 0; s < 8; ++s) {
        const int l = t + (s << 9);
        #pragma unroll
        for (int b = 0; b < 2; ++b) {
            const size_t base = (size_t)b * 6144 * 4096;
            const size_t r0 = base + (size_t)c0 * 4096;
            const size_t r1 = base + (size_t)c1 * 4096;
            const size_t r2 = base + (size_t)c2 * 4096;
            const float a0 = b2f(u[r0 + l]);
            const float a1 = (l >= 1) ? b2f(u[r0 + l - 1]) : 0.f;
            const float a2 = (l >= 2) ? b2f(u[r0 + l - 2]) : 0.f;
            const float x0v = w00 * a2 + w01 * a1 + w02 * a0 + bb0;
            const float e0 = b2f(u[r1 + l]);
            const float e1 = (l >= 1) ? b2f(u[r1 + l - 1]) : 0.f;
            const float e2 = (l >= 2) ? b2f(u[r1 + l - 2]) : 0.f;
            const float x1v = w10 * e2 + w11 * e1 + w12 * e0 + bb1;
            const float g0 = b2f(u[r2 + l]);
            const float g1 = (l >= 1) ? b2f(u[r2 + l - 1]) : 0.f;
            const float g2 = (l >= 2) ? b2f(u[r2 + l - 2]) : 0.f;
            const float vv = w20 * g2 + w21 * g1 + w22 * g0 + bb2;
            const float vg = vv * x1v;
            vgr_[b][s] = vg; x0r_[b][s] = x0v;
            if (b == 0) xr[s] = vg; else xi[s] = vg;
        }
    }
    #pragma unroll
    for (int s = 8; s < 16; ++s) { xr[s] = 0.f; xi[s] = 0.f; }

    // ---- phase 2: C = FFT(vg0 + i*vg1); pointwise *K (streamed) in C ownership; inverse to A ----
    fwd_fft(xr, xi, fre, fim, t);
    {
        const f32x4* kv = (const f32x4*)kspec + (size_t)d * 4096 + t;
        f32x4 kk[8];
        #pragma unroll
        for (int q = 0; q < 8; ++q) kk[q] = kv[q * 512];
        #pragma unroll
        for (int q = 0; q < 8; ++q) {
            float cr = xr[2 * q], ci = xi[2 * q];
            xr[2 * q] = cr * kk[q].x - ci * kk[q].y;
            xi[2 * q] = cr * kk[q].y + ci * kk[q].x;
            cr = xr[2 * q + 1]; ci = xi[2 * q + 1];
            xr[2 * q + 1] = cr * kk[q].z - ci * kk[q].w;
            xi[2 * q + 1] = cr * kk[q].w + ci * kk[q].z;
        }
    }
    inv_fft(xr, xi, fre, fim, t);

    // ---- epilogue: y = IFFT/8192; z = (y + vg*fb) * x0 ----
    const float inv_n = 1.0f / 8192.0f;
    #pragma unroll
    for (int s = 0; s < 8; ++s) {
        const int p = t + (s << 9);
        const float z0 = (xr[s] * inv_n + vgr_[0][s] * fb) * x0r_[0][s];
        const float z1 = (xi[s] * inv_n + vgr_[1][s] * fb) * x0r_[1][s];
        zb[(size_t)d * 4096 + p]          = f2b(z0);
        zb[(size_t)(2048 + d) * 4096 + p] = f2b(z1);
    }
}

// ---------- (B,D,L) bf16 -> (B,L,D) bf16 transpose ----------
__global__ __launch_bounds__(256) void transpose_kernel(const unsigned short* __restrict__ zb,
                                                        unsigned short* __restrict__ zt)
{
    __shared__ unsigned int tile[64][65];
    const int l0 = blockIdx.x * 64, d0 = blockIdx.y * 64, b = blockIdx.z;
    const int tid = threadIdx.x;
    for (int e = tid; e < 4096; e += 256) {
        const int r = e >> 6, c = e & 63;  // r = d-local, c = l-local
        tile[r][c] = zb[(size_t)(b * 2048 + d0 + r) * 4096 + l0 + c];
    }
    __syncthreads();
    for (int e = tid; e < 4096; e += 256) {
        const int r = e >> 6, c = e & 63;  // r = l-local, c = d-local
        zt[(size_t)(b * 4096 + l0 + r) * 2048 + d0 + c] = (unsigned short)tile[c][r];
    }
}

// ---------- launch ----------
// Workspace lifetime plan (256 MiB total), regions:
//   B: [0, 128 MiB)       xb(32)+wbi(24) -> kspec(128) -> ztb(32)+wbo(8)
//   A: [128, 224 MiB)     ub (96 MiB, gemm1-out .. hyena-in)
//   C: [224, 256 MiB)     kf (32 MiB, filter-out .. kfft-in) -> zbm (32 MiB)
extern "C" void kernel_launch(void* const* d_in, const int* in_sizes, int n_in,
                              void* d_out, int out_size, void* d_ws, size_t ws_size,
                              hipStream_t stream)
{
    const float* x   = (const float*)d_in[0];
    const float* ipw = (const float*)d_in[1];
    const float* ipb = (const float*)d_in[2];
    const float* sw  = (const float*)d_in[3];
    const float* sb  = (const float*)d_in[4];
    const float* w0  = (const float*)d_in[5];
    const float* b0  = (const float*)d_in[6];
    const float* fr  = (const float*)d_in[7];
    const float* w1  = (const float*)d_in[8];
    const float* b1  = (const float*)d_in[9];
    const float* w2  = (const float*)d_in[10];
    const float* b2  = (const float*)d_in[11];
    const float* w3  = (const float*)d_in[12];
    const float* fb  = (const float*)d_in[13];
    const float* opw = (const float*)d_in[14];
    const float* opb = (const float*)d_in[15];
    float* out = (float*)d_out;

    char* ws = (char*)d_ws;
    // region B (reused three times)
    unsigned short* xb    = (unsigned short*)ws;                 // 32 MiB
    unsigned short* wbi   = (unsigned short*)(ws + 33554432);    // 24 MiB
    float*          kspec = (float*)ws;                          // 128 MiB (after gemm1)
    unsigned short* ztb   = (unsigned short*)ws;                 // 32 MiB (after hyena)
    unsigned short* wbo   = (unsigned short*)(ws + 33554432);    // 8 MiB (after hyena)
    // region A
    unsigned short* ub    = (unsigned short*)(ws + 134217728);   // 96 MiB
    // region C (reused twice)
    float*          kf    = (float*)(ws + 234881024);            // 32 MiB
    unsigned short* zbm   = (unsigned short*)(ws + 234881024);   // 32 MiB (after kfft)

    cvt_f32_bf16<<<1024, 256, 0, stream>>>(x,   xb,  16777216 / 4);
    cvt_f32_bf16<<<1024, 256, 0, stream>>>(ipw, wbi, 12582912 / 4);

    // u = (x @ W_in^T + b) written transposed to (B, 3D, L); frees xb/wbi afterwards
    gemm_bf16<1><<<dim3(48, 64), 256, 0, stream>>>(xb, wbi, ipb, ub, 8192, 6144, 2048, 4096, 6144);

    filter_kernel<<<dim3(64, 8), 256, 0, stream>>>(w0, b0, fr, w1, b1, w2, b2, w3, kf);

    // K spectrum precompute (overwrites xb/wbi region)
    kfft_kernel<<<2048, 512, 0, stream>>>(kf, kspec);

    // fused conv+gate+fftconv (overwrites kf region with zbm)
    hyena_fft_kernel<<<2048, 512, 0, stream>>>(ub, kspec, sw, sb, fb, zbm);

    transpose_kernel<<<dim3(64, 32, 2), 256, 0, stream>>>(zbm, ztb);

    // out-proj weight convert after kspec is dead (its region overlaps)
    cvt_f32_bf16<<<512,  256, 0, stream>>>(opw, wbo, 4194304 / 4);

    // out = z @ W_out^T + b (f32)
    gemm_bf16<0><<<dim3(16, 64), 256, 0, stream>>>(ztb, wbo, opb, out, 8192, 2048, 2048, 4096, 2048);
}

// Round 2
// 836.224 us; speedup vs baseline: 1.1301x; 1.1301x over previous
//
#include <hip/hip_runtime.h>
#include <hip/hip_bf16.h>
#include <cstdint>
#include <cstddef>

// ---------- types ----------
typedef __attribute__((ext_vector_type(8))) short    bf16x8;   // 8 bf16 = 4 VGPRs (MFMA A/B frag)
typedef __attribute__((ext_vector_type(4))) float    f32x4;    // MFMA C/D frag
typedef __attribute__((ext_vector_type(8))) unsigned short u16x8;
typedef __attribute__((ext_vector_type(4))) float    f32v4;
typedef __attribute__((ext_vector_type(4))) unsigned short u16v4;

__device__ __forceinline__ float b2f(unsigned short v) {
    return __builtin_bit_cast(float, ((unsigned int)v) << 16);
}
__device__ __forceinline__ unsigned short f2b(float f) {
    unsigned int u = __builtin_bit_cast(unsigned int, f);
    u += 0x7fffu + ((u >> 16) & 1u);        // RNE
    return (unsigned short)(u >> 16);
}

__device__ __forceinline__ void async16(const void* g, void* l) {
    __builtin_amdgcn_global_load_lds(
        (const __attribute__((address_space(1))) unsigned int*)g,
        (__attribute__((address_space(3))) unsigned int*)l, 16, 0, 0);
}

// ---------- f32 -> bf16 convert ----------
__global__ __launch_bounds__(256) void cvt_f32_bf16(const float* __restrict__ src,
                                                    unsigned short* __restrict__ dst, int n4) {
    int i = blockIdx.x * blockDim.x + threadIdx.x;
    int stride = gridDim.x * blockDim.x;
    const f32v4* s4 = (const f32v4*)src;
    u16v4* d4 = (u16v4*)dst;
    for (; i < n4; i += stride) {
        f32v4 v = s4[i];
        u16v4 o;
        o.x = f2b(v.x); o.y = f2b(v.y); o.z = f2b(v.z); o.w = f2b(v.w);
        d4[i] = o;
    }
}

// ---------- bf16 MFMA GEMM: C[m][n] = sum_k A[m][k]*Bw[n][k] + bias[n] ----------
// MODE 0: Cout = float, row-major [M][N]
// MODE 1: Cout = bf16, "u layout": Cout[(b*CH + n)*Lseq + l], m = b*Lseq + l (tile never straddles b)
template <int MODE>
__global__ __launch_bounds__(256, 2) void gemm_bf16(
    const unsigned short* __restrict__ A,   // M x K bf16 row-major
    const unsigned short* __restrict__ Bw,  // N x K bf16 row-major
    const float* __restrict__ bias,         // N
    void* __restrict__ Cout,
    int M, int N, int K, int Lseq, int CH)
{
    constexpr int SMEM_N = (MODE == 1) ? 16384 : 8192;
    __shared__ unsigned short smem[SMEM_N];  // A tile [128][32] @0, B tile [128][32] @4096 (ushort idx)

    const int tid  = threadIdx.x;
    const int w    = tid >> 6;
    const int lane = tid & 63;
    const int quad = lane >> 4;
    const int lq   = lane & 15;
    const int n0 = blockIdx.x * 128;
    const int m0 = blockIdx.y * 128;
    const int wave_m = w & 1, wave_n = w >> 1;

    // staging: each wave copies 2KB of A + 2KB of B per K-step, 16B/lane/inst
    const int rSub = w * 32 + (lane >> 2);
    const int kcol = (lane & 3) * 8;
    const unsigned short* pA0 = A  + (size_t)(m0 + rSub)      * K + kcol;
    const unsigned short* pA1 = A  + (size_t)(m0 + rSub + 16) * K + kcol;
    const unsigned short* pB0 = Bw + (size_t)(n0 + rSub)      * K + kcol;
    const unsigned short* pB1 = Bw + (size_t)(n0 + rSub + 16) * K + kcol;
    char* sb = (char*)smem;
    char* dA0 = sb + w * 2048;
    char* dA1 = sb + w * 2048 + 1024;
    char* dB0 = sb + 8192 + w * 2048;
    char* dB1 = sb + 8192 + w * 2048 + 1024;

    f32x4 acc[4][4] = {};

    const int nIter = K >> 5;
    for (int kt = 0; kt < nIter; ++kt) {
        async16(pA0, dA0); async16(pA1, dA1);
        async16(pB0, dB0); async16(pB1, dB1);
        pA0 += 32; pA1 += 32; pB0 += 32; pB1 += 32;
        __syncthreads();   // drains vmcnt before LDS reads
        bf16x8 af[4], bw[4];
        #pragma unroll
        for (int i = 0; i < 4; ++i) {
            af[i] = *(const bf16x8*)&smem[(wave_m * 64 + i * 16 + lq) * 32 + quad * 8];
            bw[i] = *(const bf16x8*)&smem[4096 + (wave_n * 64 + i * 16 + lq) * 32 + quad * 8];
        }
        #pragma unroll
        for (int i = 0; i < 4; ++i)
            #pragma unroll
            for (int j = 0; j < 4; ++j)
                acc[i][j] = __builtin_amdgcn_mfma_f32_16x16x32_bf16(af[i], bw[j], acc[i][j], 0, 0, 0);
        __syncthreads();   // protect smem before next staging
    }

    if (MODE == 0) {
        float* out = (float*)Cout;
        #pragma unroll
        for (int j = 0; j < 4; ++j) {
            const int col = n0 + wave_n * 64 + j * 16 + lq;
            const float bv = bias[col];
            #pragma unroll
            for (int i = 0; i < 4; ++i) {
                const int rowb = m0 + wave_m * 64 + i * 16 + quad * 4;
                f32x4 c = acc[i][j];
                out[(size_t)(rowb + 0) * N + col] = c.x + bv;
                out[(size_t)(rowb + 1) * N + col] = c.y + bv;
                out[(size_t)(rowb + 2) * N + col] = c.z + bv;
                out[(size_t)(rowb + 3) * N + col] = c.w + bv;
            }
        }
    } else {
        // transpose through LDS so output rows (fixed channel, contiguous l) store coalesced
        #pragma unroll
        for (int j = 0; j < 4; ++j) {
            const int nl = wave_n * 64 + j * 16 + lq;
            const float bv = bias[n0 + nl];
            #pragma unroll
            for (int i = 0; i < 4; ++i) {
                const int ml = wave_m * 64 + i * 16 + quad * 4;
                f32x4 c = acc[i][j];
                smem[nl * 128 + ml + 0] = f2b(c.x + bv);
                smem[nl * 128 + ml + 1] = f2b(c.y + bv);
                smem[nl * 128 + ml + 2] = f2b(c.z + bv);
                smem[nl * 128 + ml + 3] = f2b(c.w + bv);
            }
        }
        __syncthreads();
        unsigned short* uo = (unsigned short*)Cout;
        const int bI = m0 >> 12;        // 4096 rows per batch
        const int l0 = m0 & 4095;
        // full 128x128 tile: 2048 chunks of 8 ushorts (16B/lane, coalesced)
        for (int e = tid; e < 2048; e += 256) {
            const int nl = e >> 4, seg = e & 15;
            u16x8 v = *(const u16x8*)&smem[nl * 128 + seg * 8];
            *(u16x8*)&uo[(size_t)(bI * CH + n0 + nl) * Lseq + l0 + seg * 8] = v;
        }
    }
}

// ---------- Hyena filter k(D,L) ----------
__global__ __launch_bounds__(256) void filter_kernel(
    const float* __restrict__ w0, const float* __restrict__ b0,
    const float* __restrict__ freq,
    const float* __restrict__ w1, const float* __restrict__ b1,
    const float* __restrict__ w2, const float* __restrict__ b2,
    const float* __restrict__ w3, float* __restrict__ kf)
{
    __shared__ float ha[64][64];
    __shared__ float hb[64][64];
    const int tid = threadIdx.x;
    const int l0 = blockIdx.x * 64;
    const int d0 = blockIdx.y * 256;
    const int l  = tid & 63;
    const int lg = l0 + l;
    const float tt = (float)lg * (1.0f / 4095.0f);
    const float wang = 6.283185307179586f * (float)lg * (1.0f / 4096.0f);
    const float a  = 1e-4f * wang;
    const float z0 = tt, z1 = cosf(a), z2 = -sinf(a);

    for (int e = tid; e < 4096; e += 256) {
        const int dim = e >> 6;
        float pre = z0 * w0[dim * 3] + z1 * w0[dim * 3 + 1] + z2 * w0[dim * 3 + 2] + b0[dim];
        ha[dim][l] = sinf(freq[dim] * pre);
    }
    __syncthreads();
    for (int e = tid; e < 4096; e += 256) {
        const int dim = e >> 6;
        float acc = b1[dim];
        #pragma unroll
        for (int jj = 0; jj < 64; ++jj) acc += w1[dim * 64 + jj] * ha[jj][l];
        hb[dim][l] = sinf(freq[dim] * acc);
    }
    __syncthreads();
    for (int e = tid; e < 4096; e += 256) {
        const int dim = e >> 6;
        float acc = b2[dim];
        #pragma unroll
        for (int jj = 0; jj < 64; ++jj) acc += w2[dim * 64 + jj] * hb[jj][l];
        ha[dim][l] = sinf(freq[dim] * acc);
    }
    __syncthreads();
    for (int d = d0 + (tid >> 6); d < d0 + 256; d += 4) {
        float acc = 0.f;
        #pragma unroll
        for (int jj = 0; jj < 64; ++jj) acc += w3[d * 64 + jj] * ha[jj][l];
        // deltas = linspace(ln(.01)/1.5, ln(.01)/0.3, 2048); decay = exp(-t*|delta|)
        const float delta = fabsf(-3.0701134573253944f + (-5.999245642062483e-3f) * (float)d);
        kf[(size_t)d * 4096 + lg] = acc * __expf(-tt * delta);
    }
}

// ================= register-resident 8192-pt FFT (512 thr, 16 pts/thr) =================
// Ownerships: A: p = t + 512 s | B: p = (t>>5)*512 + (t&31) + 32 s | C: p = 16 t + j
// DIF forward ends bit-reversed-contiguous (C); inverse DIT consumes C and ends at A.
// LDS padded idx + (idx>>5): all three access patterns are <=2-way (free) bank aliasing.
#define PIDX(i) ((i) + ((i) >> 5))

__device__ __forceinline__ void bfly_f(float& r1, float& i1, float& r2, float& i2, float wr, float wi) {
    float ur = r1, ui = i1, vr = r2, vi = i2;
    r1 = ur + vr; i1 = ui + vi;
    float dr = ur - vr, di = ui - vi;
    r2 = dr * wr - di * wi;
    i2 = dr * wi + di * wr;
}
__device__ __forceinline__ void bfly_i(float& r1, float& i1, float& r2, float& i2, float wr, float wi) {
    float vr = r2 * wr - i2 * wi, vi = r2 * wi + i2 * wr;
    float ur = r1, ui = i1;
    r1 = ur + vr; i1 = ui + vi;
    r2 = ur - vr; i2 = ui - vi;
}

// stage hm = STR*DS; j = tt + STR*(s mod DS); theta = -pi*j/hm (fwd) / +pi*j/hm (inv)
template <int DS, int STR>
__device__ __forceinline__ void fwd_stage(float* re, float* im, int tt) {
    float wr[8], wi[8];
    constexpr float c = -3.14159265358979f / (float)(STR * DS);
    #pragma unroll
    for (int k = 0; k < DS; ++k) __sincosf(c * (float)(tt + STR * k), &wi[k], &wr[k]);
    #pragma unroll
    for (int s = 0; s < 16; ++s)
        if ((s & DS) == 0)
            bfly_f(re[s], im[s], re[s + DS], im[s + DS], wr[s & (DS - 1)], wi[s & (DS - 1)]);
}
template <int DS, int STR>
__device__ __forceinline__ void inv_stage(float* re, float* im, int tt) {
    float wr[8], wi[8];
    constexpr float c = 3.14159265358979f / (float)(STR * DS);
    #pragma unroll
    for (int k = 0; k < DS; ++k) __sincosf(c * (float)(tt + STR * k), &wi[k], &wr[k]);
    #pragma unroll
    for (int s = 0; s < 16; ++s)
        if ((s & DS) == 0)
            bfly_i(re[s], im[s], re[s + DS], im[s + DS], wr[s & (DS - 1)], wi[s & (DS - 1)]);
}

__device__ __forceinline__ void xchg(float* re, float* im, float* fre, float* fim,
                                     int wbase, int wstr, int rbase, int rstr) {
    __syncthreads();           // protect prior reads of fre/fim
    #pragma unroll
    for (int s = 0; s < 16; ++s) {
        const int i = wbase + wstr * s;
        fre[PIDX(i)] = re[s]; fim[PIDX(i)] = im[s];
    }
    __syncthreads();
    #pragma unroll
    for (int s = 0; s < 16; ++s) {
        const int i = rbase + rstr * s;
        re[s] = fre[PIDX(i)]; im[s] = fim[PIDX(i)];
    }
}

__device__ __forceinline__ void fwd_fft(float* re, float* im, float* fre, float* fim, int t) {
    const int off = t & 31, seg = t >> 5;
    fwd_stage<8, 512>(re, im, t);
    fwd_stage<4, 512>(re, im, t);
    fwd_stage<2, 512>(re, im, t);
    fwd_stage<1, 512>(re, im, t);
    xchg(re, im, fre, fim, t, 512, seg * 512 + off, 32);        // A -> B
    fwd_stage<8, 32>(re, im, off);
    fwd_stage<4, 32>(re, im, off);
    fwd_stage<2, 32>(re, im, off);
    fwd_stage<1, 32>(re, im, off);
    {   // hm = 16 (m = 32) across threads t ^ 16; j = off & 15 (thread-constant)
        float wr, wi;
        __sincosf(-3.14159265358979f * (float)(off & 15) / 16.0f, &wi, &wr);
        const bool hi = (off & 16) != 0;
        #pragma unroll
        for (int s = 0; s < 16; ++s) {
            float rr = __shfl_xor(re[s], 16);
            float ri = __shfl_xor(im[s], 16);
            if (!hi) { re[s] += rr; im[s] += ri; }
            else {
                float dr = rr - re[s], di = ri - im[s];
                re[s] = dr * wr - di * wi;
                im[s] = dr * wi + di * wr;
            }
        }
    }
    xchg(re, im, fre, fim, seg * 512 + off, 32, 16 * t, 1);     // B -> C
    fwd_stage<8, 1>(re, im, 0);
    fwd_stage<4, 1>(re, im, 0);
    fwd_stage<2, 1>(re, im, 0);
    fwd_stage<1, 1>(re, im, 0);
}

__device__ __forceinline__ void inv_fft(float* re, float* im, float* fre, float* fim, int t) {
    const int off = t & 31, seg = t >> 5;
    inv_stage<1, 1>(re, im, 0);
    inv_stage<2, 1>(re, im, 0);
    inv_stage<4, 1>(re, im, 0);
    inv_stage<8, 1>(re, im, 0);
    xchg(re, im, fre, fim, 16 * t, 1, seg * 512 + off, 32);     // C -> B
    {   // hm = 16 (m = 32), conj twiddle; v' = W * x[p+16]
        float wr, wi;
        __sincosf(3.14159265358979f * (float)(off & 15) / 16.0f, &wi, &wr);
        const bool hi = (off & 16) != 0;
        #pragma unroll
        for (int s = 0; s < 16; ++s) {
            float rr = __shfl_xor(re[s], 16);
            float ri = __shfl_xor(im[s], 16);
            if (!hi) {           // u = own, v' = W * recv
                float vr = rr * wr - ri * wi, vi = rr * wi + ri * wr;
                re[s] += vr; im[s] += vi;
            } else {             // u = recv, v' = W * own
                float vr = re[s] * wr - im[s] * wi, vi = re[s] * wi + im[s] * wr;
                re[s] = rr - vr; im[s] = ri - vi;
            }
        }
    }
    inv_stage<1, 32>(re, im, off);
    inv_stage<2, 32>(re, im, off);
    inv_stage<4, 32>(re, im, off);
    inv_stage<8, 32>(re, im, off);
    xchg(re, im, fre, fim, seg * 512 + off, 32, t, 512);        // B -> A
    inv_stage<1, 512>(re, im, t);
    inv_stage<2, 512>(re, im, t);
    inv_stage<4, 512>(re, im, t);
    inv_stage<8, 512>(re, im, t);
}

// ---------- K-spectrum precompute: kspec[d] = FFT_8192(zero-padded k_d) ----------
// Layout: q-major f32x4 per (d, q, t): kspec4[d*4096 + q*512 + t] = {Kr[16t+2q], Ki[16t+2q],
// Kr[16t+2q+1], Ki[16t+2q+1]} (C ownership) -> per-instruction lane-contiguous on both sides.
// NOTE launch_bounds arg2: empirically (r1) arg2=4 with 512-thr blocks capped VGPR at 64
// (CUDA blocks-per-CU semantics) and spilled the register FFT. arg2=2 -> cap 128 = 2 blocks/CU.
__global__ __launch_bounds__(512, 2) void kfft_kernel(
    const float* __restrict__ kf,   // (D, L) f32
    float* __restrict__ kspec)      // (D, 8192) complex, packed as above
{
    __shared__ float fre[8448];
    __shared__ float fim[8448];
    const int t = threadIdx.x;
    const int d = blockIdx.x;
    float kr[16], ki[16];
    #pragma unroll
    for (int s = 0; s < 16; ++s) {
        kr[s] = (s < 8) ? kf[(size_t)d * 4096 + t + 512 * s] : 0.f;
        ki[s] = 0.f;
    }
    fwd_fft(kr, ki, fre, fim, t);
    f32x4* kv = (f32x4*)kspec + (size_t)d * 4096 + t;
    #pragma unroll
    for (int q = 0; q < 8; ++q) {
        f32x4 o;
        o.x = kr[2 * q]; o.y = ki[2 * q];
        o.z = kr[2 * q + 1]; o.w = ki[2 * q + 1];
        kv[q * 512] = o;
    }
}

// ---------- fused: short conv + gate + fftconv + bias + x0 gate -> zb (B,D,L) bf16 ----------
// LDS = fre/fim only (67,584 B) -> 2 blocks/CU; K spectrum streamed from global.
__global__ __launch_bounds__(512, 2) void hyena_fft_kernel(
    const unsigned short* __restrict__ u,   // (B, 3D, L) bf16
    const float* __restrict__ kspec,        // (D, 8192) complex, q-major f32x4
    const float* __restrict__ sw,           // (3D, 1, 3)
    const float* __restrict__ sbv,          // (3D)
    const float* __restrict__ fbias,        // (D)
    unsigned short* __restrict__ zb)        // (B, D, L) bf16
{
    __shared__ float fre[8448];
    __shared__ float fim[8448];
    const int t = threadIdx.x;
    const int d = blockIdx.x;

    // ---- phase 1: short conv (causal taps w0*u[l-2]+w1*u[l-1]+w2*u[l]) + gating, A ownership ----
    const int c0 = d, c1 = 2048 + d, c2 = 4096 + d;
    const float w00 = sw[c0*3+0], w01 = sw[c0*3+1], w02 = sw[c0*3+2], bb0 = sbv[c0];
    const float w10 = sw[c1*3+0], w11 = sw[c1*3+1], w12 = sw[c1*3+2], bb1 = sbv[c1];
    const float w20 = sw[c2*3+0], w21 = sw[c2*3+1], w22 = sw[c2*3+2], bb2 = sbv[c2];
    const float fb = fbias[d];

    float vgr_[2][8], x0r_[2][8];
    float xr[16], xi[16];
    #pragma unroll
    for (int s = 0; s < 8; ++s) {
        const int l = t + (s << 9);
        #pragma unroll
        for (int b = 0; b < 2; ++b) {
            const size_t base = (size_t)b * 6144 * 4096;
            const size_t r0 = base + (size_t)c0 * 4096;
            const size_t r1 = base + (size_t)c1 * 4096;
            const size_t r2 = base + (size_t)c2 * 4096;
            const float a0 = b2f(u[r0 + l]);
            const float a1 = (l >= 1) ? b2f(u[r0 + l - 1]) : 0.f;
            const float a2 = (l >= 2) ? b2f(u[r0 + l - 2]) : 0.f;
            const float x0v = w00 * a2 + w01 * a1 + w02 * a0 + bb0;
            const float e0 = b2f(u[r1 + l]);
            const float e1 = (l >= 1) ? b2f(u[r1 + l - 1]) : 0.f;
            const float e2 = (l >= 2) ? b2f(u[r1 + l - 2]) : 0.f;
            const float x1v = w10 * e2 + w11 * e1 + w12 * e0 + bb1;
            const float g0 = b2f(u[r2 + l]);
            const float g1 = (l >= 1) ? b2f(u[r2 + l - 1]) : 0.f;
            const float g2 = (l >= 2) ? b2f(u[r2 + l - 2]) : 0.f;
            const float vv = w20 * g2 + w21 * g1 + w22 * g0 + bb2;
            const float vg = vv * x1v;
            vgr_[b][s] = vg; x0r_[b][s] = x0v;
            if (b == 0) xr[s] = vg; else xi[s] = vg;
        }
    }
    #pragma unroll
    for (int s = 8; s < 16; ++s) { xr[s] = 0.f; xi[s] = 0.f; }

    // ---- phase 2: C = FFT(vg0 + i*vg1); pointwise *K (streamed) in C ownership; inverse to A ----
    fwd_fft(xr, xi, fre, fim, t);
    {
        const f32x4* kv = (const f32x4*)kspec + (size_t)d * 4096 + t;
        f32x4 kk[8];
        #pragma unroll
        for (int q = 0; q < 8; ++q) kk[q] = kv[q * 512];
        #pragma unroll
        for (int q = 0; q < 8; ++q) {
            float cr = xr[2 * q], ci = xi[2 * q];
            xr[2 * q] = cr * kk[q].x - ci * kk[q].y;
            xi[2 * q] = cr * kk[q].y + ci * kk[q].x;
            cr = xr[2 * q + 1]; ci = xi[2 * q + 1];
            xr[2 * q + 1] = cr * kk[q].z - ci * kk[q].w;
            xi[2 * q + 1] = cr * kk[q].w + ci * kk[q].z;
        }
    }
    inv_fft(xr, xi, fre, fim, t);

    // ---- epilogue: y = IFFT/8192; z = (y + vg*fb) * x0 ----
    const float inv_n = 1.0f / 8192.0f;
    #pragma unroll
    for (int s = 0; s < 8; ++s) {
        const int p = t + (s << 9);
        const float z0 = (xr[s] * inv_n + vgr_[0][s] * fb) * x0r_[0][s];
        const float z1 = (xi[s] * inv_n + vgr_[1][s] * fb) * x0r_[1][s];
        zb[(size_t)d * 4096 + p]          = f2b(z0);
        zb[(size_t)(2048 + d) * 4096 + p] = f2b(z1);
    }
}

// ---------- (B,D,L) bf16 -> (B,L,D) bf16 transpose ----------
__global__ __launch_bounds__(256) void transpose_kernel(const unsigned short* __restrict__ zb,
                                                        unsigned short* __restrict__ zt)
{
    __shared__ unsigned int tile[64][65];
    const int l0 = blockIdx.x * 64, d0 = blockIdx.y * 64, b = blockIdx.z;
    const int tid = threadIdx.x;
    for (int e = tid; e < 4096; e += 256) {
        const int r = e >> 6, c = e & 63;  // r = d-local, c = l-local
        tile[r][c] = zb[(size_t)(b * 2048 + d0 + r) * 4096 + l0 + c];
    }
    __syncthreads();
    for (int e = tid; e < 4096; e += 256) {
        const int r = e >> 6, c = e & 63;  // r = l-local, c = d-local
        zt[(size_t)(b * 4096 + l0 + r) * 2048 + d0 + c] = (unsigned short)tile[c][r];
    }
}

// ---------- launch ----------
// Workspace lifetime plan (256 MiB total), regions:
//   B: [0, 128 MiB)       xb(32)+wbi(24) -> kspec(128) -> ztb(32)+wbo(8)
//   A: [128, 224 MiB)     ub (96 MiB, gemm1-out .. hyena-in)
//   C: [224, 256 MiB)     kf (32 MiB, filter-out .. kfft-in) -> zbm (32 MiB)
extern "C" void kernel_launch(void* const* d_in, const int* in_sizes, int n_in,
                              void* d_out, int out_size, void* d_ws, size_t ws_size,
                              hipStream_t stream)
{
    const float* x   = (const float*)d_in[0];
    const float* ipw = (const float*)d_in[1];
    const float* ipb = (const float*)d_in[2];
    const float* sw  = (const float*)d_in[3];
    const float* sb  = (const float*)d_in[4];
    const float* w0  = (const float*)d_in[5];
    const float* b0  = (const float*)d_in[6];
    const float* fr  = (const float*)d_in[7];
    const float* w1  = (const float*)d_in[8];
    const float* b1  = (const float*)d_in[9];
    const float* w2  = (const float*)d_in[10];
    const float* b2  = (const float*)d_in[11];
    const float* w3  = (const float*)d_in[12];
    const float* fb  = (const float*)d_in[13];
    const float* opw = (const float*)d_in[14];
    const float* opb = (const float*)d_in[15];
    float* out = (float*)d_out;

    char* ws = (char*)d_ws;
    // region B (reused three times)
    unsigned short* xb    = (unsigned short*)ws;                 // 32 MiB
    unsigned short* wbi   = (unsigned short*)(ws + 33554432);    // 24 MiB
    float*          kspec = (float*)ws;                          // 128 MiB (after gemm1)
    unsigned short* ztb   = (unsigned short*)ws;                 // 32 MiB (after hyena)
    unsigned short* wbo   = (unsigned short*)(ws + 33554432);    // 8 MiB (after hyena)
    // region A
    unsigned short* ub    = (unsigned short*)(ws + 134217728);   // 96 MiB
    // region C (reused twice)
    float*          kf    = (float*)(ws + 234881024);            // 32 MiB
    unsigned short* zbm   = (unsigned short*)(ws + 234881024);   // 32 MiB (after kfft)

    cvt_f32_bf16<<<1024, 256, 0, stream>>>(x,   xb,  16777216 / 4);
    cvt_f32_bf16<<<1024, 256, 0, stream>>>(ipw, wbi, 12582912 / 4);

    // u = (x @ W_in^T + b) written transposed to (B, 3D, L); frees xb/wbi afterwards
    gemm_bf16<1><<<dim3(48, 64), 256, 0, stream>>>(xb, wbi, ipb, ub, 8192, 6144, 2048, 4096, 6144);

    filter_kernel<<<dim3(64, 8), 256, 0, stream>>>(w0, b0, fr, w1, b1, w2, b2, w3, kf);

    // K spectrum precompute (overwrites xb/wbi region)
    kfft_kernel<<<2048, 512, 0, stream>>>(kf, kspec);

    // fused conv+gate+fftconv (overwrites kf region with zbm)
    hyena_fft_kernel<<<2048, 512, 0, stream>>>(ub, kspec, sw, sb, fb, zbm);

    transpose_kernel<<<dim3(64, 32, 2), 256, 0, stream>>>(zbm, ztb);

    // out-proj weight convert after kspec is dead (its region overlaps)
    cvt_f32_bf16<<<512,  256, 0, stream>>>(opw, wbo, 4194304 / 4);

    // out = z @ W_out^T + b (f32)
    gemm_bf16<0><<<dim3(16, 64), 256, 0, stream>>>(ztb, wbo, opb, out, 8192, 2048, 2048, 4096, 2048);
}

// Round 3
// 765.919 us; speedup vs baseline: 1.2339x; 1.0918x over previous
//
#include <hip/hip_runtime.h>
#include <hip/hip_bf16.h>
#include <cstdint>
#include <cstddef>

// ---------- types ----------
typedef __attribute__((ext_vector_type(8))) short    bf16x8;   // 8 bf16 = 4 VGPRs (MFMA A/B frag)
typedef __attribute__((ext_vector_type(4))) float    f32x4;    // MFMA C/D frag
typedef __attribute__((ext_vector_type(8))) unsigned short u16x8;
typedef __attribute__((ext_vector_type(4))) float    f32v4;
typedef __attribute__((ext_vector_type(4))) unsigned short u16v4;

__device__ __forceinline__ float b2f(unsigned short v) {
    return __builtin_bit_cast(float, ((unsigned int)v) << 16);
}
__device__ __forceinline__ unsigned short f2b(float f) {
    unsigned int u = __builtin_bit_cast(unsigned int, f);
    u += 0x7fffu + ((u >> 16) & 1u);        // RNE
    return (unsigned short)(u >> 16);
}

__device__ __forceinline__ void async16(const void* g, void* l) {
    __builtin_amdgcn_global_load_lds(
        (const __attribute__((address_space(1))) unsigned int*)g,
        (__attribute__((address_space(3))) unsigned int*)l, 16, 0, 0);
}

// ---------- f32 -> bf16 convert ----------
__global__ __launch_bounds__(256) void cvt_f32_bf16(const float* __restrict__ src,
                                                    unsigned short* __restrict__ dst, int n4) {
    int i = blockIdx.x * blockDim.x + threadIdx.x;
    int stride = gridDim.x * blockDim.x;
    const f32v4* s4 = (const f32v4*)src;
    u16v4* d4 = (u16v4*)dst;
    for (; i < n4; i += stride) {
        f32v4 v = s4[i];
        u16v4 o;
        o.x = f2b(v.x); o.y = f2b(v.y); o.z = f2b(v.z); o.w = f2b(v.w);
        d4[i] = o;
    }
}

// ============ 256x256-tile 8-phase bf16 MFMA GEMM (m201-style schedule) ============
// C[m][n] = sum_k A[m][k]*Bw[n][k] + bias[n]
// 512 threads = 8 waves (2 M x 4 N); per-wave C = 128x64 = acc[8][4] f32x4.
// BK=64; LDS double-buffered by K-tile parity: buf b at b*65536: A 32KB @0, B 32KB @32768.
// A LDS row order permutes 64-row blocks {0,2,1,3} so half h0 = rows read by quads 0-1.
// XOR swizzle: LDS[L][u] holds global unit u^(L&7) (pre-swizzled global source, linear dest).
// Schedule per iteration (2 K-tiles t0=2i buf0, t1=2i+1 buf1), 8 phases:
//   P1: LDB(0)+LDA(0,q0) | stage A(t1)h1            P5: LDB(1)+LDA(1,q0) | stage A(t0+2)h1
//   P2: LDA(0,q1)        | stage B(t0+2)h0          P6: LDA(1,q1)        | stage B(t1+2)h0
//   P3: LDA(0,q2)        | stage B(t0+2)h1          P7: LDA(1,q2)        | stage B(t1+2)h1
//   P4: LDA(0,q3)        | stage A(t0+2)h0 +vmcnt6  P8: LDA(1,q3)        | stage A(t1+2)h0 +vmcnt6
// Region lifetimes verified: every stage targets a region last read >=1 phase earlier;
// vmcnt(6) at P4 drains through P1's loads, at P8 drains through P5's. Last iter: vmcnt(0).
// MODE 0: Cout = float row-major [M][N].  MODE 1: bf16 u-layout Cout[(bI*CH+n)*Lseq+l].
template <int MODE>
__global__ __launch_bounds__(512, 1) void gemm256(
    const unsigned short* __restrict__ A,   // M x K bf16 row-major
    const unsigned short* __restrict__ Bw,  // N x K bf16 row-major
    const float* __restrict__ bias,         // N
    void* __restrict__ Cout,
    int M, int N, int K, int Lseq, int CH, int ntn)
{
    constexpr int SMEM_BYTES = (MODE == 1) ? 135168 : 131072;   // epi needs 256*264*2
    __shared__ char smemc[SMEM_BYTES];

    const int tid = threadIdx.x;
    const int w   = tid >> 6;           // wave 0..7
    const int l   = tid & 63;
    const int wm  = w & 1;              // 2 waves in M
    const int wn  = w >> 1;             // 4 waves in N
    const int quad = l >> 4;
    const int lq   = l & 15;

    // XCD-aware bijective swizzle (grid % 8 == 0 for both uses)
    int id = blockIdx.x;
    const int q8 = gridDim.x >> 3;
    id = (id & 7) * q8 + (id >> 3);
    const int bx = id % ntn, by = id / ntn;
    const int n0 = bx * 256, m0 = by * 256;

    // swizzled ds_read unit indices (global k-unit kk*4+quad lives at LDS unit ^ (row&7))
    const int su0 = quad ^ (lq & 7);
    const int su1 = su0 ^ 4;

    // staging: per wave 2 insts per (operand, half); lane fetches pre-swizzled global unit
    uint32_t offAe[2][2], offBe[2][2];
    int dA[2][2], dB[2][2];
    #pragma unroll
    for (int h = 0; h < 2; ++h)
        #pragma unroll
        for (int c = 0; c < 2; ++c) {
            const int Lr = h * 128 + w * 16 + c * 8 + (l >> 3);
            const int gA = ((Lr & 64) << 1) | ((Lr & 128) >> 1) | (Lr & 63);  // block perm {0,2,1,3}
            const int u  = (l & 7) ^ (l >> 3);
            offAe[h][c] = (uint32_t)(m0 + gA) * (uint32_t)K + (uint32_t)(u * 8);
            offBe[h][c] = (uint32_t)(n0 + Lr) * (uint32_t)K + (uint32_t)(u * 8);
            const int rb = (h * 128 + w * 16 + c * 8) * 128;   // LDS byte row base (wave-uniform)
            dA[h][c] = rb;
            dB[h][c] = 32768 + rb;
        }

#define STAGE_A(bs, h, tile) do { \
    async16(A + offAe[h][0] + (size_t)(tile) * 64, smemc + ((bs) * 65536 + dA[h][0])); \
    async16(A + offAe[h][1] + (size_t)(tile) * 64, smemc + ((bs) * 65536 + dA[h][1])); \
} while (0)
#define STAGE_B(bs, h, tile) do { \
    async16(Bw + offBe[h][0] + (size_t)(tile) * 64, smemc + ((bs) * 65536 + dB[h][0])); \
    async16(Bw + offBe[h][1] + (size_t)(tile) * 64, smemc + ((bs) * 65536 + dB[h][1])); \
} while (0)

    f32x4 acc[8][4] = {};
    bf16x8 bw[4][2], a[2][2];

#define LDB8(bs) do { \
    _Pragma("unroll") for (int j = 0; j < 4; ++j) { \
        const int Lr = wn * 64 + j * 16 + lq; \
        bw[j][0] = *(const bf16x8*)(smemc + (bs) * 65536 + 32768 + Lr * 128 + su0 * 16); \
        bw[j][1] = *(const bf16x8*)(smemc + (bs) * 65536 + 32768 + Lr * 128 + su1 * 16); \
    } } while (0)
#define LDA4(bs, q) do { \
    _Pragma("unroll") for (int mf = 0; mf < 2; ++mf) { \
        const int g = wm * 128 + (q) * 32 + mf * 16 + lq; \
        const int Lr = ((g & 64) << 1) | ((g & 128) >> 1) | (g & 63); \
        a[mf][0] = *(const bf16x8*)(smemc + (bs) * 65536 + Lr * 128 + su0 * 16); \
        a[mf][1] = *(const bf16x8*)(smemc + (bs) * 65536 + Lr * 128 + su1 * 16); \
    } } while (0)
#define MFMA16(q) do { \
    _Pragma("unroll") for (int mf = 0; mf < 2; ++mf) \
    _Pragma("unroll") for (int j = 0; j < 4; ++j) \
    _Pragma("unroll") for (int kk = 0; kk < 2; ++kk) \
        acc[(q) * 2 + mf][j] = __builtin_amdgcn_mfma_f32_16x16x32_bf16(a[mf][kk], bw[j][kk], acc[(q) * 2 + mf][j], 0, 0, 0); \
} while (0)
#define PHASE_SYNC() do { \
    __builtin_amdgcn_s_barrier(); \
    asm volatile("s_waitcnt lgkmcnt(0)" ::: "memory"); \
    __builtin_amdgcn_sched_barrier(0); \
    __builtin_amdgcn_s_setprio(1); \
} while (0)
#define PHASE_END() do { \
    __builtin_amdgcn_s_setprio(0); \
    __builtin_amdgcn_s_barrier(); \
} while (0)
#define PHASE_END_DRAIN(lastf) do { \
    __builtin_amdgcn_s_setprio(0); \
    if (lastf) asm volatile("s_waitcnt vmcnt(0)" ::: "memory"); \
    else       asm volatile("s_waitcnt vmcnt(6)" ::: "memory"); \
    __builtin_amdgcn_s_barrier(); \
} while (0)

    // prologue: tile0 full + tile1 all-but-Ah1 (14 loads/wave); drain tile0, keep 6 in flight
    STAGE_B(0, 0, 0); STAGE_B(0, 1, 0); STAGE_A(0, 0, 0); STAGE_A(0, 1, 0);
    STAGE_B(1, 0, 1); STAGE_B(1, 1, 1); STAGE_A(1, 0, 1);
    asm volatile("s_waitcnt vmcnt(6)" ::: "memory");
    __builtin_amdgcn_s_barrier();

    const int nIt = K >> 7;             // 2 K-tiles (BK=64) per iteration
    for (int i = 0; i < nIt; ++i) {
        const bool last = (i == nIt - 1);
        const int t0 = 2 * i, t1 = 2 * i + 1;
        // P1
        LDB8(0); LDA4(0, 0); STAGE_A(1, 1, t1);
        PHASE_SYNC(); MFMA16(0); PHASE_END();
        // P2
        LDA4(0, 1); if (!last) STAGE_B(0, 0, t0 + 2);
        PHASE_SYNC(); MFMA16(1); PHASE_END();
        // P3
        LDA4(0, 2); if (!last) STAGE_B(0, 1, t0 + 2);
        PHASE_SYNC(); MFMA16(2); PHASE_END();
        // P4
        LDA4(0, 3); if (!last) STAGE_A(0, 0, t0 + 2);
        PHASE_SYNC(); MFMA16(3); PHASE_END_DRAIN(last);
        // P5
        LDB8(1); LDA4(1, 0); if (!last) STAGE_A(0, 1, t0 + 2);
        PHASE_SYNC(); MFMA16(0); PHASE_END();
        // P6
        LDA4(1, 1); if (!last) STAGE_B(1, 0, t1 + 2);
        PHASE_SYNC(); MFMA16(1); PHASE_END();
        // P7
        LDA4(1, 2); if (!last) STAGE_B(1, 1, t1 + 2);
        PHASE_SYNC(); MFMA16(2); PHASE_END();
        // P8
        LDA4(1, 3); if (!last) STAGE_A(1, 0, t1 + 2);
        PHASE_SYNC(); MFMA16(3); PHASE_END_DRAIN(last);
    }

    if (MODE == 0) {
        float* out = (float*)Cout;
        #pragma unroll
        for (int j = 0; j < 4; ++j) {
            const int col = n0 + wn * 64 + j * 16 + lq;
            const float bv = bias[col];
            #pragma unroll
            for (int i8 = 0; i8 < 8; ++i8) {
                const int rowb = m0 + wm * 128 + i8 * 16 + quad * 4;
                f32x4 c = acc[i8][j];
                out[(size_t)(rowb + 0) * N + col] = c.x + bv;
                out[(size_t)(rowb + 1) * N + col] = c.y + bv;
                out[(size_t)(rowb + 2) * N + col] = c.z + bv;
                out[(size_t)(rowb + 3) * N + col] = c.w + bv;
            }
        }
    } else {
        // transpose through LDS (alias staging buffers; loop fully drained at last PHASE_END_DRAIN)
        unsigned short* sE = (unsigned short*)smemc;   // [256][264]
        __syncthreads();
        #pragma unroll
        for (int j = 0; j < 4; ++j) {
            const int nl = wn * 64 + j * 16 + lq;
            const float bv = bias[n0 + nl];
            #pragma unroll
            for (int i8 = 0; i8 < 8; ++i8) {
                const int ml = wm * 128 + i8 * 16 + quad * 4;
                f32x4 c = acc[i8][j];
                u16v4 pk;
                pk.x = f2b(c.x + bv); pk.y = f2b(c.y + bv);
                pk.z = f2b(c.z + bv); pk.w = f2b(c.w + bv);
                *(u16v4*)&sE[nl * 264 + ml] = pk;
            }
        }
        __syncthreads();
        unsigned short* uo = (unsigned short*)Cout;
        const int bI = m0 >> 12;        // 4096 rows per batch (M-tiles never straddle)
        const int l0 = m0 & 4095;
        for (int e = tid; e < 8192; e += 512) {
            const int nl = e >> 5, seg = e & 31;
            u16x8 v = *(const u16x8*)&sE[nl * 264 + seg * 8];
            *(u16x8*)&uo[(size_t)(bI * CH + n0 + nl) * Lseq + l0 + seg * 8] = v;
        }
    }
#undef STAGE_A
#undef STAGE_B
#undef LDB8
#undef LDA4
#undef MFMA16
#undef PHASE_SYNC
#undef PHASE_END
#undef PHASE_END_DRAIN
}

// ---------- Hyena filter k(D,L) ----------
__global__ __launch_bounds__(256) void filter_kernel(
    const float* __restrict__ w0, const float* __restrict__ b0,
    const float* __restrict__ freq,
    const float* __restrict__ w1, const float* __restrict__ b1,
    const float* __restrict__ w2, const float* __restrict__ b2,
    const float* __restrict__ w3, float* __restrict__ kf)
{
    __shared__ float ha[64][64];
    __shared__ float hb[64][64];
    const int tid = threadIdx.x;
    const int l0 = blockIdx.x * 64;
    const int d0 = blockIdx.y * 256;
    const int l  = tid & 63;
    const int lg = l0 + l;
    const float tt = (float)lg * (1.0f / 4095.0f);
    const float wang = 6.283185307179586f * (float)lg * (1.0f / 4096.0f);
    const float a  = 1e-4f * wang;
    const float z0 = tt, z1 = cosf(a), z2 = -sinf(a);

    for (int e = tid; e < 4096; e += 256) {
        const int dim = e >> 6;
        float pre = z0 * w0[dim * 3] + z1 * w0[dim * 3 + 1] + z2 * w0[dim * 3 + 2] + b0[dim];
        ha[dim][l] = sinf(freq[dim] * pre);
    }
    __syncthreads();
    for (int e = tid; e < 4096; e += 256) {
        const int dim = e >> 6;
        float acc = b1[dim];
        #pragma unroll
        for (int jj = 0; jj < 64; ++jj) acc += w1[dim * 64 + jj] * ha[jj][l];
        hb[dim][l] = sinf(freq[dim] * acc);
    }
    __syncthreads();
    for (int e = tid; e < 4096; e += 256) {
        const int dim = e >> 6;
        float acc = b2[dim];
        #pragma unroll
        for (int jj = 0; jj < 64; ++jj) acc += w2[dim * 64 + jj] * hb[jj][l];
        ha[dim][l] = sinf(freq[dim] * acc);
    }
    __syncthreads();
    for (int d = d0 + (tid >> 6); d < d0 + 256; d += 4) {
        float acc = 0.f;
        #pragma unroll
        for (int jj = 0; jj < 64; ++jj) acc += w3[d * 64 + jj] * ha[jj][l];
        // deltas = linspace(ln(.01)/1.5, ln(.01)/0.3, 2048); decay = exp(-t*|delta|)
        const float delta = fabsf(-3.0701134573253944f + (-5.999245642062483e-3f) * (float)d);
        kf[(size_t)d * 4096 + lg] = acc * __expf(-tt * delta);
    }
}

// ================= register-resident 8192-pt FFT (512 thr, 16 pts/thr) =================
// Ownerships: A: p = t + 512 s | B: p = (t>>5)*512 + (t&31) + 32 s | C: p = 16 t + j
// DIF forward ends bit-reversed-contiguous (C); inverse DIT consumes C and ends at A.
// LDS padded idx + (idx>>5): all three access patterns are <=2-way (free) bank aliasing.
#define PIDX(i) ((i) + ((i) >> 5))

__device__ __forceinline__ void bfly_f(float& r1, float& i1, float& r2, float& i2, float wr, float wi) {
    float ur = r1, ui = i1, vr = r2, vi = i2;
    r1 = ur + vr; i1 = ui + vi;
    float dr = ur - vr, di = ui - vi;
    r2 = dr * wr - di * wi;
    i2 = dr * wi + di * wr;
}
__device__ __forceinline__ void bfly_i(float& r1, float& i1, float& r2, float& i2, float wr, float wi) {
    float vr = r2 * wr - i2 * wi, vi = r2 * wi + i2 * wr;
    float ur = r1, ui = i1;
    r1 = ur + vr; i1 = ui + vi;
    r2 = ur - vr; i2 = ui - vi;
}

// stage hm = STR*DS; j = tt + STR*(s mod DS); theta = -pi*j/hm (fwd) / +pi*j/hm (inv)
template <int DS, int STR>
__device__ __forceinline__ void fwd_stage(float* re, float* im, int tt) {
    float wr[8], wi[8];
    constexpr float c = -3.14159265358979f / (float)(STR * DS);
    #pragma unroll
    for (int k = 0; k < DS; ++k) __sincosf(c * (float)(tt + STR * k), &wi[k], &wr[k]);
    #pragma unroll
    for (int s = 0; s < 16; ++s)
        if ((s & DS) == 0)
            bfly_f(re[s], im[s], re[s + DS], im[s + DS], wr[s & (DS - 1)], wi[s & (DS - 1)]);
}
template <int DS, int STR>
__device__ __forceinline__ void inv_stage(float* re, float* im, int tt) {
    float wr[8], wi[8];
    constexpr float c = 3.14159265358979f / (float)(STR * DS);
    #pragma unroll
    for (int k = 0; k < DS; ++k) __sincosf(c * (float)(tt + STR * k), &wi[k], &wr[k]);
    #pragma unroll
    for (int s = 0; s < 16; ++s)
        if ((s & DS) == 0)
            bfly_i(re[s], im[s], re[s + DS], im[s + DS], wr[s & (DS - 1)], wi[s & (DS - 1)]);
}

__device__ __forceinline__ void xchg(float* re, float* im, float* fre, float* fim,
                                     int wbase, int wstr, int rbase, int rstr) {
    __syncthreads();           // protect prior reads of fre/fim
    #pragma unroll
    for (int s = 0; s < 16; ++s) {
        const int i = wbase + wstr * s;
        fre[PIDX(i)] = re[s]; fim[PIDX(i)] = im[s];
    }
    __syncthreads();
    #pragma unroll
    for (int s = 0; s < 16; ++s) {
        const int i = rbase + rstr * s;
        re[s] = fre[PIDX(i)]; im[s] = fim[PIDX(i)];
    }
}

__device__ __forceinline__ void fwd_fft(float* re, float* im, float* fre, float* fim, int t) {
    const int off = t & 31, seg = t >> 5;
    fwd_stage<8, 512>(re, im, t);
    fwd_stage<4, 512>(re, im, t);
    fwd_stage<2, 512>(re, im, t);
    fwd_stage<1, 512>(re, im, t);
    xchg(re, im, fre, fim, t, 512, seg * 512 + off, 32);        // A -> B
    fwd_stage<8, 32>(re, im, off);
    fwd_stage<4, 32>(re, im, off);
    fwd_stage<2, 32>(re, im, off);
    fwd_stage<1, 32>(re, im, off);
    {   // hm = 16 (m = 32) across threads t ^ 16; j = off & 15 (thread-constant)
        float wr, wi;
        __sincosf(-3.14159265358979f * (float)(off & 15) / 16.0f, &wi, &wr);
        const bool hi = (off & 16) != 0;
        #pragma unroll
        for (int s = 0; s < 16; ++s) {
            float rr = __shfl_xor(re[s], 16);
            float ri = __shfl_xor(im[s], 16);
            if (!hi) { re[s] += rr; im[s] += ri; }
            else {
                float dr = rr - re[s], di = ri - im[s];
                re[s] = dr * wr - di * wi;
                im[s] = dr * wi + di * wr;
            }
        }
    }
    xchg(re, im, fre, fim, seg * 512 + off, 32, 16 * t, 1);     // B -> C
    fwd_stage<8, 1>(re, im, 0);
    fwd_stage<4, 1>(re, im, 0);
    fwd_stage<2, 1>(re, im, 0);
    fwd_stage<1, 1>(re, im, 0);
}

__device__ __forceinline__ void inv_fft(float* re, float* im, float* fre, float* fim, int t) {
    const int off = t & 31, seg = t >> 5;
    inv_stage<1, 1>(re, im, 0);
    inv_stage<2, 1>(re, im, 0);
    inv_stage<4, 1>(re, im, 0);
    inv_stage<8, 1>(re, im, 0);
    xchg(re, im, fre, fim, 16 * t, 1, seg * 512 + off, 32);     // C -> B
    {   // hm = 16 (m = 32), conj twiddle; v' = W * x[p+16]
        float wr, wi;
        __sincosf(3.14159265358979f * (float)(off & 15) / 16.0f, &wi, &wr);
        const bool hi = (off & 16) != 0;
        #pragma unroll
        for (int s = 0; s < 16; ++s) {
            float rr = __shfl_xor(re[s], 16);
            float ri = __shfl_xor(im[s], 16);
            if (!hi) {           // u = own, v' = W * recv
                float vr = rr * wr - ri * wi, vi = rr * wi + ri * wr;
                re[s] += vr; im[s] += vi;
            } else {             // u = recv, v' = W * own
                float vr = re[s] * wr - im[s] * wi, vi = re[s] * wi + im[s] * wr;
                re[s] = rr - vr; im[s] = ri - vi;
            }
        }
    }
    inv_stage<1, 32>(re, im, off);
    inv_stage<2, 32>(re, im, off);
    inv_stage<4, 32>(re, im, off);
    inv_stage<8, 32>(re, im, off);
    xchg(re, im, fre, fim, seg * 512 + off, 32, t, 512);        // B -> A
    inv_stage<1, 512>(re, im, t);
    inv_stage<2, 512>(re, im, t);
    inv_stage<4, 512>(re, im, t);
    inv_stage<8, 512>(re, im, t);
}

// ---------- K-spectrum precompute: kspec[d] = FFT_8192(zero-padded k_d) ----------
// Layout: q-major f32x4 per (d, q, t): kspec4[d*4096 + q*512 + t] = {Kr[16t+2q], Ki[16t+2q],
// Kr[16t+2q+1], Ki[16t+2q+1]} (C ownership) -> per-instruction lane-contiguous on both sides.
// NOTE launch_bounds arg2: empirically (r1) arg2=4 with 512-thr blocks capped VGPR at 64
// (CUDA blocks-per-CU semantics) and spilled the register FFT. arg2=2 -> cap 128 = 2 blocks/CU.
__global__ __launch_bounds__(512, 2) void kfft_kernel(
    const float* __restrict__ kf,   // (D, L) f32
    float* __restrict__ kspec)      // (D, 8192) complex, packed as above
{
    __shared__ float fre[8448];
    __shared__ float fim[8448];
    const int t = threadIdx.x;
    const int d = blockIdx.x;
    float kr[16], ki[16];
    #pragma unroll
    for (int s = 0; s < 16; ++s) {
        kr[s] = (s < 8) ? kf[(size_t)d * 4096 + t + 512 * s] : 0.f;
        ki[s] = 0.f;
    }
    fwd_fft(kr, ki, fre, fim, t);
    f32x4* kv = (f32x4*)kspec + (size_t)d * 4096 + t;
    #pragma unroll
    for (int q = 0; q < 8; ++q) {
        f32x4 o;
        o.x = kr[2 * q]; o.y = ki[2 * q];
        o.z = kr[2 * q + 1]; o.w = ki[2 * q + 1];
        kv[q * 512] = o;
    }
}

// ---------- fused: short conv + gate + fftconv + bias + x0 gate -> zb (B,D,L) bf16 ----------
// LDS = fre/fim only (67,584 B) -> 2 blocks/CU; K spectrum streamed from global.
__global__ __launch_bounds__(512, 2) void hyena_fft_kernel(
    const unsigned short* __restrict__ u,   // (B, 3D, L) bf16
    const float* __restrict__ kspec,        // (D, 8192) complex, q-major f32x4
    const float* __restrict__ sw,           // (3D, 1, 3)
    const float* __restrict__ sbv,          // (3D)
    const float* __restrict__ fbias,        // (D)
    unsigned short* __restrict__ zb)        // (B, D, L) bf16
{
    __shared__ float fre[8448];
    __shared__ float fim[8448];
    const int t = threadIdx.x;
    const int d = blockIdx.x;

    // ---- phase 1: short conv (causal taps w0*u[l-2]+w1*u[l-1]+w2*u[l]) + gating, A ownership ----
    const int c0 = d, c1 = 2048 + d, c2 = 4096 + d;
    const float w00 = sw[c0*3+0], w01 = sw[c0*3+1], w02 = sw[c0*3+2], bb0 = sbv[c0];
    const float w10 = sw[c1*3+0], w11 = sw[c1*3+1], w12 = sw[c1*3+2], bb1 = sbv[c1];
    const float w20 = sw[c2*3+0], w21 = sw[c2*3+1], w22 = sw[c2*3+2], bb2 = sbv[c2];
    const float fb = fbias[d];

    float vgr_[2][8], x0r_[2][8];
    float xr[16], xi[16];
    #pragma unroll
    for (int s = 0; s < 8; ++s) {
        const int l = t + (s << 9);
        #pragma unroll
        for (int b = 0; b < 2; ++b) {
            const size_t base = (size_t)b * 6144 * 4096;
            const size_t r0 = base + (size_t)c0 * 4096;
            const size_t r1 = base + (size_t)c1 * 4096;
            const size_t r2 = base + (size_t)c2 * 4096;
            const float a0 = b2f(u[r0 + l]);
            const float a1 = (l >= 1) ? b2f(u[r0 + l - 1]) : 0.f;
            const float a2 = (l >= 2) ? b2f(u[r0 + l - 2]) : 0.f;
            const float x0v = w00 * a2 + w01 * a1 + w02 * a0 + bb0;
            const float e0 = b2f(u[r1 + l]);
            const float e1 = (l >= 1) ? b2f(u[r1 + l - 1]) : 0.f;
            const float e2 = (l >= 2) ? b2f(u[r1 + l - 2]) : 0.f;
            const float x1v = w10 * e2 + w11 * e1 + w12 * e0 + bb1;
            const float g0 = b2f(u[r2 + l]);
            const float g1 = (l >= 1) ? b2f(u[r2 + l - 1]) : 0.f;
            const float g2 = (l >= 2) ? b2f(u[r2 + l - 2]) : 0.f;
            const float vv = w20 * g2 + w21 * g1 + w22 * g0 + bb2;
            const float vg = vv * x1v;
            vgr_[b][s] = vg; x0r_[b][s] = x0v;
            if (b == 0) xr[s] = vg; else xi[s] = vg;
        }
    }
    #pragma unroll
    for (int s = 8; s < 16; ++s) { xr[s] = 0.f; xi[s] = 0.f; }

    // ---- phase 2: C = FFT(vg0 + i*vg1); pointwise *K (streamed) in C ownership; inverse to A ----
    fwd_fft(xr, xi, fre, fim, t);
    {
        const f32x4* kv = (const f32x4*)kspec + (size_t)d * 4096 + t;
        f32x4 kk[8];
        #pragma unroll
        for (int q = 0; q < 8; ++q) kk[q] = kv[q * 512];
        #pragma unroll
        for (int q = 0; q < 8; ++q) {
            float cr = xr[2 * q], ci = xi[2 * q];
            xr[2 * q] = cr * kk[q].x - ci * kk[q].y;
            xi[2 * q] = cr * kk[q].y + ci * kk[q].x;
            cr = xr[2 * q + 1]; ci = xi[2 * q + 1];
            xr[2 * q + 1] = cr * kk[q].z - ci * kk[q].w;
            xi[2 * q + 1] = cr * kk[q].w + ci * kk[q].z;
        }
    }
    inv_fft(xr, xi, fre, fim, t);

    // ---- epilogue: y = IFFT/8192; z = (y + vg*fb) * x0 ----
    const float inv_n = 1.0f / 8192.0f;
    #pragma unroll
    for (int s = 0; s < 8; ++s) {
        const int p = t + (s << 9);
        const float z0 = (xr[s] * inv_n + vgr_[0][s] * fb) * x0r_[0][s];
        const float z1 = (xi[s] * inv_n + vgr_[1][s] * fb) * x0r_[1][s];
        zb[(size_t)d * 4096 + p]          = f2b(z0);
        zb[(size_t)(2048 + d) * 4096 + p] = f2b(z1);
    }
}

// ---------- (B,D,L) bf16 -> (B,L,D) bf16 transpose ----------
__global__ __launch_bounds__(256) void transpose_kernel(const unsigned short* __restrict__ zb,
                                                        unsigned short* __restrict__ zt)
{
    __shared__ unsigned int tile[64][65];
    const int l0 = blockIdx.x * 64, d0 = blockIdx.y * 64, b = blockIdx.z;
    const int tid = threadIdx.x;
    for (int e = tid; e < 4096; e += 256) {
        const int r = e >> 6, c = e & 63;  // r = d-local, c = l-local
        tile[r][c] = zb[(size_t)(b * 2048 + d0 + r) * 4096 + l0 + c];
    }
    __syncthreads();
    for (int e = tid; e < 4096; e += 256) {
        const int r = e >> 6, c = e & 63;  // r = l-local, c = d-local
        zt[(size_t)(b * 4096 + l0 + r) * 2048 + d0 + c] = (unsigned short)tile[c][r];
    }
}

// ---------- launch ----------
// Workspace lifetime plan (256 MiB total), regions:
//   B: [0, 128 MiB)       xb(32)+wbi(24) -> kspec(128) -> ztb(32)+wbo(8)
//   A: [128, 224 MiB)     ub (96 MiB, gemm1-out .. hyena-in)
//   C: [224, 256 MiB)     kf (32 MiB, filter-out .. kfft-in) -> zbm (32 MiB)
extern "C" void kernel_launch(void* const* d_in, const int* in_sizes, int n_in,
                              void* d_out, int out_size, void* d_ws, size_t ws_size,
                              hipStream_t stream)
{
    const float* x   = (const float*)d_in[0];
    const float* ipw = (const float*)d_in[1];
    const float* ipb = (const float*)d_in[2];
    const float* sw  = (const float*)d_in[3];
    const float* sb  = (const float*)d_in[4];
    const float* w0  = (const float*)d_in[5];
    const float* b0  = (const float*)d_in[6];
    const float* fr  = (const float*)d_in[7];
    const float* w1  = (const float*)d_in[8];
    const float* b1  = (const float*)d_in[9];
    const float* w2  = (const float*)d_in[10];
    const float* b2  = (const float*)d_in[11];
    const float* w3  = (const float*)d_in[12];
    const float* fb  = (const float*)d_in[13];
    const float* opw = (const float*)d_in[14];
    const float* opb = (const float*)d_in[15];
    float* out = (float*)d_out;

    char* ws = (char*)d_ws;
    // region B (reused three times)
    unsigned short* xb    = (unsigned short*)ws;                 // 32 MiB
    unsigned short* wbi   = (unsigned short*)(ws + 33554432);    // 24 MiB
    float*          kspec = (float*)ws;                          // 128 MiB (after gemm1)
    unsigned short* ztb   = (unsigned short*)ws;                 // 32 MiB (after hyena)
    unsigned short* wbo   = (unsigned short*)(ws + 33554432);    // 8 MiB (after hyena)
    // region A
    unsigned short* ub    = (unsigned short*)(ws + 134217728);   // 96 MiB
    // region C (reused twice)
    float*          kf    = (float*)(ws + 234881024);            // 32 MiB
    unsigned short* zbm   = (unsigned short*)(ws + 234881024);   // 32 MiB (after kfft)

    cvt_f32_bf16<<<1024, 256, 0, stream>>>(x,   xb,  16777216 / 4);
    cvt_f32_bf16<<<1024, 256, 0, stream>>>(ipw, wbi, 12582912 / 4);

    // u = (x @ W_in^T + b) written transposed to (B, 3D, L); frees xb/wbi afterwards
    // grid = (8192/256) * (6144/256) = 32 * 24 = 768 (1D, XCD-swizzled in-kernel)
    gemm256<1><<<768, 512, 0, stream>>>(xb, wbi, ipb, ub, 8192, 6144, 2048, 4096, 6144, 24);

    filter_kernel<<<dim3(64, 8), 256, 0, stream>>>(w0, b0, fr, w1, b1, w2, b2, w3, kf);

    // K spectrum precompute (overwrites xb/wbi region)
    kfft_kernel<<<2048, 512, 0, stream>>>(kf, kspec);

    // fused conv+gate+fftconv (overwrites kf region with zbm)
    hyena_fft_kernel<<<2048, 512, 0, stream>>>(ub, kspec, sw, sb, fb, zbm);

    transpose_kernel<<<dim3(64, 32, 2), 256, 0, stream>>>(zbm, ztb);

    // out-proj weight convert after kspec is dead (its region overlaps)
    cvt_f32_bf16<<<512,  256, 0, stream>>>(opw, wbo, 4194304 / 4);

    // out = z @ W_out^T + b (f32); grid = 32 * 8 = 256
    gemm256<0><<<256, 512, 0, stream>>>(ztb, wbo, opb, out, 8192, 2048, 2048, 4096, 2048, 8);
}

// Round 4
// 749.860 us; speedup vs baseline: 1.2603x; 1.0214x over previous
//
#include <hip/hip_runtime.h>
#include <hip/hip_bf16.h>
#include <cstdint>
#include <cstddef>

// ---------- types ----------
typedef __attribute__((ext_vector_type(8))) short    bf16x8;   // 8 bf16 = 4 VGPRs (MFMA A/B frag)
typedef __attribute__((ext_vector_type(4))) float    f32x4;    // MFMA C/D frag
typedef __attribute__((ext_vector_type(8))) unsigned short u16x8;
typedef __attribute__((ext_vector_type(4))) float    f32v4;
typedef __attribute__((ext_vector_type(4))) unsigned short u16v4;

__device__ __forceinline__ float b2f(unsigned short v) {
    return __builtin_bit_cast(float, ((unsigned int)v) << 16);
}
__device__ __forceinline__ unsigned short f2b(float f) {
    unsigned int u = __builtin_bit_cast(unsigned int, f);
    u += 0x7fffu + ((u >> 16) & 1u);        // RNE
    return (unsigned short)(u >> 16);
}

__device__ __forceinline__ void async16(const void* g, void* l) {
    __builtin_amdgcn_global_load_lds(
        (const __attribute__((address_space(1))) unsigned int*)g,
        (__attribute__((address_space(3))) unsigned int*)l, 16, 0, 0);
}

// ---------- f32 -> bf16 convert ----------
__global__ __launch_bounds__(256) void cvt_f32_bf16(const float* __restrict__ src,
                                                    unsigned short* __restrict__ dst, int n4) {
    int i = blockIdx.x * blockDim.x + threadIdx.x;
    int stride = gridDim.x * blockDim.x;
    const f32v4* s4 = (const f32v4*)src;
    u16v4* d4 = (u16v4*)dst;
    for (; i < n4; i += stride) {
        f32v4 v = s4[i];
        u16v4 o;
        o.x = f2b(v.x); o.y = f2b(v.y); o.z = f2b(v.z); o.w = f2b(v.w);
        d4[i] = o;
    }
}

// ============ 256x256-tile 8-phase bf16 MFMA GEMM (m201-style schedule) ============
// C[m][n] = sum_k A[m][k]*Bw[n][k] + bias[n]
// 512 threads = 8 waves (2 M x 4 N); per-wave C = 128x64 = acc[8][4] f32x4.
// BK=64; LDS double-buffered by K-tile parity: buf b at b*65536: A 32KB @0, B 32KB @32768.
// A LDS row order permutes 64-row blocks {0,2,1,3} so half h0 = rows read by quads 0-1.
// XOR swizzle: LDS[L][u] holds global unit u^(L&7) (pre-swizzled global source, linear dest).
// Schedule per iteration (2 K-tiles t0=2i buf0, t1=2i+1 buf1), 8 phases:
//   P1: LDB(0)+LDA(0,q0) | stage A(t1)h1            P5: LDB(1)+LDA(1,q0) | stage A(t0+2)h1
//   P2: LDA(0,q1)        | stage B(t0+2)h0          P6: LDA(1,q1)        | stage B(t1+2)h0
//   P3: LDA(0,q2)        | stage B(t0+2)h1          P7: LDA(1,q2)        | stage B(t1+2)h1
//   P4: LDA(0,q3)        | stage A(t0+2)h0 +vmcnt6  P8: LDA(1,q3)        | stage A(t1+2)h0 +vmcnt6
// Region lifetimes verified: every stage targets a region last read >=1 phase earlier;
// vmcnt(6) at P4 drains through P1's loads, at P8 drains through P5's. Last iter: vmcnt(0).
// MODE 0: Cout = float row-major [M][N].  MODE 1: bf16 u-layout Cout[(bI*CH+n)*Lseq+l].
template <int MODE>
__global__ __launch_bounds__(512, 1) void gemm256(
    const unsigned short* __restrict__ A,   // M x K bf16 row-major
    const unsigned short* __restrict__ Bw,  // N x K bf16 row-major
    const float* __restrict__ bias,         // N
    void* __restrict__ Cout,
    int M, int N, int K, int Lseq, int CH, int ntn)
{
    constexpr int SMEM_BYTES = (MODE == 1) ? 135168 : 131072;   // epi needs 256*264*2
    __shared__ char smemc[SMEM_BYTES];

    const int tid = threadIdx.x;
    const int w   = tid >> 6;           // wave 0..7
    const int l   = tid & 63;
    const int wm  = w & 1;              // 2 waves in M
    const int wn  = w >> 1;             // 4 waves in N
    const int quad = l >> 4;
    const int lq   = l & 15;

    // XCD-aware bijective swizzle (grid % 8 == 0 for both uses)
    int id = blockIdx.x;
    const int q8 = gridDim.x >> 3;
    id = (id & 7) * q8 + (id >> 3);
    const int bx = id % ntn, by = id / ntn;
    const int n0 = bx * 256, m0 = by * 256;

    // swizzled ds_read unit indices (global k-unit kk*4+quad lives at LDS unit ^ (row&7))
    const int su0 = quad ^ (lq & 7);
    const int su1 = su0 ^ 4;

    // staging: per wave 2 insts per (operand, half); lane fetches pre-swizzled global unit
    uint32_t offAe[2][2], offBe[2][2];
    int dA[2][2], dB[2][2];
    #pragma unroll
    for (int h = 0; h < 2; ++h)
        #pragma unroll
        for (int c = 0; c < 2; ++c) {
            const int Lr = h * 128 + w * 16 + c * 8 + (l >> 3);
            const int gA = ((Lr & 64) << 1) | ((Lr & 128) >> 1) | (Lr & 63);  // block perm {0,2,1,3}
            const int u  = (l & 7) ^ (l >> 3);
            offAe[h][c] = (uint32_t)(m0 + gA) * (uint32_t)K + (uint32_t)(u * 8);
            offBe[h][c] = (uint32_t)(n0 + Lr) * (uint32_t)K + (uint32_t)(u * 8);
            const int rb = (h * 128 + w * 16 + c * 8) * 128;   // LDS byte row base (wave-uniform)
            dA[h][c] = rb;
            dB[h][c] = 32768 + rb;
        }

#define STAGE_A(bs, h, tile) do { \
    async16(A + offAe[h][0] + (size_t)(tile) * 64, smemc + ((bs) * 65536 + dA[h][0])); \
    async16(A + offAe[h][1] + (size_t)(tile) * 64, smemc + ((bs) * 65536 + dA[h][1])); \
} while (0)
#define STAGE_B(bs, h, tile) do { \
    async16(Bw + offBe[h][0] + (size_t)(tile) * 64, smemc + ((bs) * 65536 + dB[h][0])); \
    async16(Bw + offBe[h][1] + (size_t)(tile) * 64, smemc + ((bs) * 65536 + dB[h][1])); \
} while (0)

    f32x4 acc[8][4] = {};
    bf16x8 bw[4][2], a[2][2];

#define LDB8(bs) do { \
    _Pragma("unroll") for (int j = 0; j < 4; ++j) { \
        const int Lr = wn * 64 + j * 16 + lq; \
        bw[j][0] = *(const bf16x8*)(smemc + (bs) * 65536 + 32768 + Lr * 128 + su0 * 16); \
        bw[j][1] = *(const bf16x8*)(smemc + (bs) * 65536 + 32768 + Lr * 128 + su1 * 16); \
    } } while (0)
#define LDA4(bs, q) do { \
    _Pragma("unroll") for (int mf = 0; mf < 2; ++mf) { \
        const int g = wm * 128 + (q) * 32 + mf * 16 + lq; \
        const int Lr = ((g & 64) << 1) | ((g & 128) >> 1) | (g & 63); \
        a[mf][0] = *(const bf16x8*)(smemc + (bs) * 65536 + Lr * 128 + su0 * 16); \
        a[mf][1] = *(const bf16x8*)(smemc + (bs) * 65536 + Lr * 128 + su1 * 16); \
    } } while (0)
#define MFMA16(q) do { \
    _Pragma("unroll") for (int mf = 0; mf < 2; ++mf) \
    _Pragma("unroll") for (int j = 0; j < 4; ++j) \
    _Pragma("unroll") for (int kk = 0; kk < 2; ++kk) \
        acc[(q) * 2 + mf][j] = __builtin_amdgcn_mfma_f32_16x16x32_bf16(a[mf][kk], bw[j][kk], acc[(q) * 2 + mf][j], 0, 0, 0); \
} while (0)
#define PHASE_SYNC() do { \
    __builtin_amdgcn_s_barrier(); \
    asm volatile("s_waitcnt lgkmcnt(0)" ::: "memory"); \
    __builtin_amdgcn_sched_barrier(0); \
    __builtin_amdgcn_s_setprio(1); \
} while (0)
#define PHASE_END() do { \
    __builtin_amdgcn_s_setprio(0); \
    __builtin_amdgcn_s_barrier(); \
} while (0)
#define PHASE_END_DRAIN(lastf) do { \
    __builtin_amdgcn_s_setprio(0); \
    if (lastf) asm volatile("s_waitcnt vmcnt(0)" ::: "memory"); \
    else       asm volatile("s_waitcnt vmcnt(6)" ::: "memory"); \
    __builtin_amdgcn_s_barrier(); \
} while (0)

    // prologue: tile0 full + tile1 all-but-Ah1 (14 loads/wave); drain tile0, keep 6 in flight
    STAGE_B(0, 0, 0); STAGE_B(0, 1, 0); STAGE_A(0, 0, 0); STAGE_A(0, 1, 0);
    STAGE_B(1, 0, 1); STAGE_B(1, 1, 1); STAGE_A(1, 0, 1);
    asm volatile("s_waitcnt vmcnt(6)" ::: "memory");
    __builtin_amdgcn_s_barrier();

    const int nIt = K >> 7;             // 2 K-tiles (BK=64) per iteration
    for (int i = 0; i < nIt; ++i) {
        const bool last = (i == nIt - 1);
        const int t0 = 2 * i, t1 = 2 * i + 1;
        // P1
        LDB8(0); LDA4(0, 0); STAGE_A(1, 1, t1);
        PHASE_SYNC(); MFMA16(0); PHASE_END();
        // P2
        LDA4(0, 1); if (!last) STAGE_B(0, 0, t0 + 2);
        PHASE_SYNC(); MFMA16(1); PHASE_END();
        // P3
        LDA4(0, 2); if (!last) STAGE_B(0, 1, t0 + 2);
        PHASE_SYNC(); MFMA16(2); PHASE_END();
        // P4
        LDA4(0, 3); if (!last) STAGE_A(0, 0, t0 + 2);
        PHASE_SYNC(); MFMA16(3); PHASE_END_DRAIN(last);
        // P5
        LDB8(1); LDA4(1, 0); if (!last) STAGE_A(0, 1, t0 + 2);
        PHASE_SYNC(); MFMA16(0); PHASE_END();
        // P6
        LDA4(1, 1); if (!last) STAGE_B(1, 0, t1 + 2);
        PHASE_SYNC(); MFMA16(1); PHASE_END();
        // P7
        LDA4(1, 2); if (!last) STAGE_B(1, 1, t1 + 2);
        PHASE_SYNC(); MFMA16(2); PHASE_END();
        // P8
        LDA4(1, 3); if (!last) STAGE_A(1, 0, t1 + 2);
        PHASE_SYNC(); MFMA16(3); PHASE_END_DRAIN(last);
    }

    if (MODE == 0) {
        float* out = (float*)Cout;
        #pragma unroll
        for (int j = 0; j < 4; ++j) {
            const int col = n0 + wn * 64 + j * 16 + lq;
            const float bv = bias[col];
            #pragma unroll
            for (int i8 = 0; i8 < 8; ++i8) {
                const int rowb = m0 + wm * 128 + i8 * 16 + quad * 4;
                f32x4 c = acc[i8][j];
                out[(size_t)(rowb + 0) * N + col] = c.x + bv;
                out[(size_t)(rowb + 1) * N + col] = c.y + bv;
                out[(size_t)(rowb + 2) * N + col] = c.z + bv;
                out[(size_t)(rowb + 3) * N + col] = c.w + bv;
            }
        }
    } else {
        // transpose through LDS (alias staging buffers; loop fully drained at last PHASE_END_DRAIN)
        unsigned short* sE = (unsigned short*)smemc;   // [256][264]
        __syncthreads();
        #pragma unroll
        for (int j = 0; j < 4; ++j) {
            const int nl = wn * 64 + j * 16 + lq;
            const float bv = bias[n0 + nl];
            #pragma unroll
            for (int i8 = 0; i8 < 8; ++i8) {
                const int ml = wm * 128 + i8 * 16 + quad * 4;
                f32x4 c = acc[i8][j];
                u16v4 pk;
                pk.x = f2b(c.x + bv); pk.y = f2b(c.y + bv);
                pk.z = f2b(c.z + bv); pk.w = f2b(c.w + bv);
                *(u16v4*)&sE[nl * 264 + ml] = pk;
            }
        }
        __syncthreads();
        unsigned short* uo = (unsigned short*)Cout;
        const int bI = m0 >> 12;        // 4096 rows per batch (M-tiles never straddle)
        const int l0 = m0 & 4095;
        for (int e = tid; e < 8192; e += 512) {
            const int nl = e >> 5, seg = e & 31;
            u16x8 v = *(const u16x8*)&sE[nl * 264 + seg * 8];
            *(u16x8*)&uo[(size_t)(bI * CH + n0 + nl) * Lseq + l0 + seg * 8] = v;
        }
    }
#undef STAGE_A
#undef STAGE_B
#undef LDB8
#undef LDA4
#undef MFMA16
#undef PHASE_SYNC
#undef PHASE_END
#undef PHASE_END_DRAIN
}

// ---------- Hyena filter k(D,L) ----------
__global__ __launch_bounds__(256) void filter_kernel(
    const float* __restrict__ w0, const float* __restrict__ b0,
    const float* __restrict__ freq,
    const float* __restrict__ w1, const float* __restrict__ b1,
    const float* __restrict__ w2, const float* __restrict__ b2,
    const float* __restrict__ w3, float* __restrict__ kf)
{
    __shared__ float ha[64][64];
    __shared__ float hb[64][64];
    const int tid = threadIdx.x;
    const int l0 = blockIdx.x * 64;
    const int d0 = blockIdx.y * 256;
    const int l  = tid & 63;
    const int lg = l0 + l;
    const float tt = (float)lg * (1.0f / 4095.0f);
    const float wang = 6.283185307179586f * (float)lg * (1.0f / 4096.0f);
    const float a  = 1e-4f * wang;
    const float z0 = tt, z1 = cosf(a), z2 = -sinf(a);

    for (int e = tid; e < 4096; e += 256) {
        const int dim = e >> 6;
        float pre = z0 * w0[dim * 3] + z1 * w0[dim * 3 + 1] + z2 * w0[dim * 3 + 2] + b0[dim];
        ha[dim][l] = sinf(freq[dim] * pre);
    }
    __syncthreads();
    for (int e = tid; e < 4096; e += 256) {
        const int dim = e >> 6;
        float acc = b1[dim];
        #pragma unroll
        for (int jj = 0; jj < 64; ++jj) acc += w1[dim * 64 + jj] * ha[jj][l];
        hb[dim][l] = sinf(freq[dim] * acc);
    }
    __syncthreads();
    for (int e = tid; e < 4096; e += 256) {
        const int dim = e >> 6;
        float acc = b2[dim];
        #pragma unroll
        for (int jj = 0; jj < 64; ++jj) acc += w2[dim * 64 + jj] * hb[jj][l];
        ha[dim][l] = sinf(freq[dim] * acc);
    }
    __syncthreads();
    for (int d = d0 + (tid >> 6); d < d0 + 256; d += 4) {
        float acc = 0.f;
        #pragma unroll
        for (int jj = 0; jj < 64; ++jj) acc += w3[d * 64 + jj] * ha[jj][l];
        // deltas = linspace(ln(.01)/1.5, ln(.01)/0.3, 2048); decay = exp(-t*|delta|)
        const float delta = fabsf(-3.0701134573253944f + (-5.999245642062483e-3f) * (float)d);
        kf[(size_t)d * 4096 + lg] = acc * __expf(-tt * delta);
    }
}

// ================= register-resident 8192-pt FFT (512 thr, 16 pts/thr) =================
// Ownerships: A: p = t + 512 s | B: p = (t>>5)*512 + (t&31) + 32 s | C: p = 16 t + j
// DIF forward ends bit-reversed-contiguous (C); inverse DIT consumes C and ends at A.
// LDS pad: +4 floats per 32 (PIDX) -> preserves 16B alignment of 8/16-aligned runs, so the
// C-side xchg and 8-contig conv I/O use ds_{read,write}_b128; all patterns stay <=2-way banked.
#define PIDX(i) ((i) + (((i) >> 5) << 2))

__device__ __forceinline__ void bfly_f(float& r1, float& i1, float& r2, float& i2, float wr, float wi) {
    float ur = r1, ui = i1, vr = r2, vi = i2;
    r1 = ur + vr; i1 = ui + vi;
    float dr = ur - vr, di = ui - vi;
    r2 = dr * wr - di * wi;
    i2 = dr * wi + di * wr;
}
__device__ __forceinline__ void bfly_i(float& r1, float& i1, float& r2, float& i2, float wr, float wi) {
    float vr = r2 * wr - i2 * wi, vi = r2 * wi + i2 * wr;
    float ur = r1, ui = i1;
    r1 = ur + vr; i1 = ui + vi;
    r2 = ur - vr; i2 = ui - vi;
}

// stage hm = STR*DS; j = tt + STR*(s mod DS); theta = -pi*j/hm (fwd) / +pi*j/hm (inv)
template <int DS, int STR>
__device__ __forceinline__ void fwd_stage(float* re, float* im, int tt) {
    float wr[8], wi[8];
    constexpr float c = -3.14159265358979f / (float)(STR * DS);
    #pragma unroll
    for (int k = 0; k < DS; ++k) __sincosf(c * (float)(tt + STR * k), &wi[k], &wr[k]);
    #pragma unroll
    for (int s = 0; s < 16; ++s)
        if ((s & DS) == 0)
            bfly_f(re[s], im[s], re[s + DS], im[s + DS], wr[s & (DS - 1)], wi[s & (DS - 1)]);
}
template <int DS, int STR>
__device__ __forceinline__ void inv_stage(float* re, float* im, int tt) {
    float wr[8], wi[8];
    constexpr float c = 3.14159265358979f / (float)(STR * DS);
    #pragma unroll
    for (int k = 0; k < DS; ++k) __sincosf(c * (float)(tt + STR * k), &wi[k], &wr[k]);
    #pragma unroll
    for (int s = 0; s < 16; ++s)
        if ((s & DS) == 0)
            bfly_i(re[s], im[s], re[s + DS], im[s + DS], wr[s & (DS - 1)], wi[s & (DS - 1)]);
}

// xchg: wstr==1 / rstr==1 (C-ownership side) vectorize to 4x b128 (16t is 16-aligned; the
// +4/32 pad keeps any 4-run inside one 32-segment contiguous and 16B-aligned).
__device__ __forceinline__ void xchg(float* re, float* im, float* fre, float* fim,
                                     int wbase, int wstr, int rbase, int rstr) {
    __syncthreads();           // protect prior reads of fre/fim
    if (wstr == 1) {
        #pragma unroll
        for (int q = 0; q < 4; ++q) {
            f32x4 vr, vi;
            vr.x = re[4*q+0]; vr.y = re[4*q+1]; vr.z = re[4*q+2]; vr.w = re[4*q+3];
            vi.x = im[4*q+0]; vi.y = im[4*q+1]; vi.z = im[4*q+2]; vi.w = im[4*q+3];
            *(f32x4*)&fre[PIDX(wbase + 4*q)] = vr;
            *(f32x4*)&fim[PIDX(wbase + 4*q)] = vi;
        }
    } else {
        #pragma unroll
        for (int s = 0; s < 16; ++s) {
            const int i = wbase + wstr * s;
            fre[PIDX(i)] = re[s]; fim[PIDX(i)] = im[s];
        }
    }
    __syncthreads();
    if (rstr == 1) {
        #pragma unroll
        for (int q = 0; q < 4; ++q) {
            f32x4 vr = *(const f32x4*)&fre[PIDX(rbase + 4*q)];
            f32x4 vi = *(const f32x4*)&fim[PIDX(rbase + 4*q)];
            re[4*q+0] = vr.x; re[4*q+1] = vr.y; re[4*q+2] = vr.z; re[4*q+3] = vr.w;
            im[4*q+0] = vi.x; im[4*q+1] = vi.y; im[4*q+2] = vi.z; im[4*q+3] = vi.w;
        }
    } else {
        #pragma unroll
        for (int s = 0; s < 16; ++s) {
            const int i = rbase + rstr * s;
            re[s] = fre[PIDX(i)]; im[s] = fim[PIDX(i)];
        }
    }
}

__device__ __forceinline__ void fwd_fft(float* re, float* im, float* fre, float* fim, int t) {
    const int off = t & 31, seg = t >> 5;
    fwd_stage<8, 512>(re, im, t);
    fwd_stage<4, 512>(re, im, t);
    fwd_stage<2, 512>(re, im, t);
    fwd_stage<1, 512>(re, im, t);
    xchg(re, im, fre, fim, t, 512, seg * 512 + off, 32);        // A -> B
    fwd_stage<8, 32>(re, im, off);
    fwd_stage<4, 32>(re, im, off);
    fwd_stage<2, 32>(re, im, off);
    fwd_stage<1, 32>(re, im, off);
    {   // hm = 16 (m = 32) across threads t ^ 16; j = off & 15 (thread-constant)
        float wr, wi;
        __sincosf(-3.14159265358979f * (float)(off & 15) / 16.0f, &wi, &wr);
        const bool hi = (off & 16) != 0;
        #pragma unroll
        for (int s = 0; s < 16; ++s) {
            float rr = __shfl_xor(re[s], 16);
            float ri = __shfl_xor(im[s], 16);
            if (!hi) { re[s] += rr; im[s] += ri; }
            else {
                float dr = rr - re[s], di = ri - im[s];
                re[s] = dr * wr - di * wi;
                im[s] = dr * wi + di * wr;
            }
        }
    }
    xchg(re, im, fre, fim, seg * 512 + off, 32, 16 * t, 1);     // B -> C
    fwd_stage<8, 1>(re, im, 0);
    fwd_stage<4, 1>(re, im, 0);
    fwd_stage<2, 1>(re, im, 0);
    fwd_stage<1, 1>(re, im, 0);
}

__device__ __forceinline__ void inv_fft(float* re, float* im, float* fre, float* fim, int t) {
    const int off = t & 31, seg = t >> 5;
    inv_stage<1, 1>(re, im, 0);
    inv_stage<2, 1>(re, im, 0);
    inv_stage<4, 1>(re, im, 0);
    inv_stage<8, 1>(re, im, 0);
    xchg(re, im, fre, fim, 16 * t, 1, seg * 512 + off, 32);     // C -> B
    {   // hm = 16 (m = 32), conj twiddle; v' = W * x[p+16]
        float wr, wi;
        __sincosf(3.14159265358979f * (float)(off & 15) / 16.0f, &wi, &wr);
        const bool hi = (off & 16) != 0;
        #pragma unroll
        for (int s = 0; s < 16; ++s) {
            float rr = __shfl_xor(re[s], 16);
            float ri = __shfl_xor(im[s], 16);
            if (!hi) {           // u = own, v' = W * recv
                float vr = rr * wr - ri * wi, vi = rr * wi + ri * wr;
                re[s] += vr; im[s] += vi;
            } else {             // u = recv, v' = W * own
                float vr = re[s] * wr - im[s] * wi, vi = re[s] * wi + im[s] * wr;
                re[s] = rr - vr; im[s] = ri - vi;
            }
        }
    }
    inv_stage<1, 32>(re, im, off);
    inv_stage<2, 32>(re, im, off);
    inv_stage<4, 32>(re, im, off);
    inv_stage<8, 32>(re, im, off);
    xchg(re, im, fre, fim, seg * 512 + off, 32, t, 512);        // B -> A
    inv_stage<1, 512>(re, im, t);
    inv_stage<2, 512>(re, im, t);
    inv_stage<4, 512>(re, im, t);
    inv_stage<8, 512>(re, im, t);
}

// ---------- K-spectrum precompute: kspec[d] = FFT_8192(zero-padded k_d) ----------
// Layout: q-major f32x4 per (d, q, t): kspec4[d*4096 + q*512 + t] = {Kr[16t+2q], Ki[16t+2q],
// Kr[16t+2q+1], Ki[16t+2q+1]} (C ownership) -> per-instruction lane-contiguous on both sides.
// NOTE launch_bounds arg2: empirically (r1) arg2=4 with 512-thr blocks capped VGPR at 64
// (CUDA blocks-per-CU semantics) and spilled the register FFT. arg2=2 -> cap 128 = 2 blocks/CU.
__global__ __launch_bounds__(512, 2) void kfft_kernel(
    const float* __restrict__ kf,   // (D, L) f32
    float* __restrict__ kspec)      // (D, 8192) complex, packed as above
{
    __shared__ __align__(16) float fre[9216];
    __shared__ __align__(16) float fim[9216];
    const int t = threadIdx.x;
    const int d = blockIdx.x;
    float kr[16], ki[16];
    #pragma unroll
    for (int s = 0; s < 16; ++s) {
        kr[s] = (s < 8) ? kf[(size_t)d * 4096 + t + 512 * s] : 0.f;
        ki[s] = 0.f;
    }
    fwd_fft(kr, ki, fre, fim, t);
    f32x4* kv = (f32x4*)kspec + (size_t)d * 4096 + t;
    #pragma unroll
    for (int q = 0; q < 8; ++q) {
        f32x4 o;
        o.x = kr[2 * q]; o.y = ki[2 * q];
        o.z = kr[2 * q + 1]; o.w = ki[2 * q + 1];
        kv[q * 512] = o;
    }
}

// causal 3-tap depthwise conv on an 8-contiguous chunk [lb, lb+8) of one channel row
__device__ __forceinline__ void conv8(const unsigned short* __restrict__ row, int lb,
                                      float W0, float W1, float W2, float BB,
                                      float* __restrict__ out) {
    u16x8 v8 = *(const u16x8*)(row + lb);
    float f[8];
    #pragma unroll
    for (int j = 0; j < 8; ++j) f[j] = b2f(v8[j]);
    const float fm1 = (lb >= 1) ? b2f(row[lb - 1]) : 0.f;
    const float fm2 = (lb >= 2) ? b2f(row[lb - 2]) : 0.f;
    out[0] = W0 * fm2 + W1 * fm1 + W2 * f[0] + BB;
    out[1] = W0 * fm1 + W1 * f[0] + W2 * f[1] + BB;
    #pragma unroll
    for (int j = 2; j < 8; ++j) out[j] = W0 * f[j - 2] + W1 * f[j - 1] + W2 * f[j] + BB;
}

// ---------- fused: short conv + gate + fftconv + bias + x0 gate -> zb (B,D,L) bf16 ----------
// Conv + epilogue run in 8-contiguous ownership (l in [8t,8t+8)) for u16x8 global I/O;
// LDS redistribution (through fre/fim) bridges to/from the FFT's A ownership.
// LDS = fre/fim only (73,728 B) -> 2 blocks/CU; K spectrum streamed from global.
__global__ __launch_bounds__(512, 2) void hyena_fft_kernel(
    const unsigned short* __restrict__ u,   // (B, 3D, L) bf16
    const float* __restrict__ kspec,        // (D, 8192) complex, q-major f32x4
    const float* __restrict__ sw,           // (3D, 1, 3)
    const float* __restrict__ sbv,          // (3D)
    const float* __restrict__ fbias,        // (D)
    unsigned short* __restrict__ zb)        // (B, D, L) bf16
{
    __shared__ __align__(16) float fre[9216];
    __shared__ __align__(16) float fim[9216];
    const int t = threadIdx.x;
    const int d = blockIdx.x;
    const int lb = t << 3;

    // ---- phase 1: short conv + gating, 8-contig ownership, vectorized loads ----
    const int c0 = d, c1 = 2048 + d, c2 = 4096 + d;
    const float w00 = sw[c0*3+0], w01 = sw[c0*3+1], w02 = sw[c0*3+2], bb0 = sbv[c0];
    const float w10 = sw[c1*3+0], w11 = sw[c1*3+1], w12 = sw[c1*3+2], bb1 = sbv[c1];
    const float w20 = sw[c2*3+0], w21 = sw[c2*3+1], w22 = sw[c2*3+2], bb2 = sbv[c2];
    const float fb = fbias[d];

    float vgc[2][8], x0c[2][8];     // stay live (8-contig) through both FFTs
    #pragma unroll
    for (int b = 0; b < 2; ++b) {
        const size_t base = (size_t)b * 6144 * 4096;
        float a_[8], e_[8], g_[8];
        conv8(u + base + (size_t)c0 * 4096, lb, w00, w01, w02, bb0, a_);
        conv8(u + base + (size_t)c1 * 4096, lb, w10, w11, w12, bb1, e_);
        conv8(u + base + (size_t)c2 * 4096, lb, w20, w21, w22, bb2, g_);
        #pragma unroll
        for (int j = 0; j < 8; ++j) { x0c[b][j] = a_[j]; vgc[b][j] = g_[j] * e_[j]; }
    }

    // ---- redistribute vg (8-contig -> A ownership) through LDS; first LDS use, no pre-barrier ----
    #pragma unroll
    for (int q = 0; q < 2; ++q) {
        f32x4 vr, vi;
        vr.x = vgc[0][4*q+0]; vr.y = vgc[0][4*q+1]; vr.z = vgc[0][4*q+2]; vr.w = vgc[0][4*q+3];
        vi.x = vgc[1][4*q+0]; vi.y = vgc[1][4*q+1]; vi.z = vgc[1][4*q+2]; vi.w = vgc[1][4*q+3];
        *(f32x4*)&fre[PIDX(lb + 4*q)] = vr;
        *(f32x4*)&fim[PIDX(lb + 4*q)] = vi;
    }
    __syncthreads();
    float xr[16], xi[16];
    #pragma unroll
    for (int s = 0; s < 8; ++s) {
        xr[s] = fre[PIDX(t + (s << 9))];
        xi[s] = fim[PIDX(t + (s << 9))];
    }
    #pragma unroll
    for (int s = 8; s < 16; ++s) { xr[s] = 0.f; xi[s] = 0.f; }

    // ---- C = FFT(vg0 + i*vg1); pointwise *K (streamed) in C ownership; inverse to A ----
    fwd_fft(xr, xi, fre, fim, t);    // leading __syncthreads protects redistribution reads
    {
        const f32x4* kv = (const f32x4*)kspec + (size_t)d * 4096 + t;
        f32x4 kk[8];
        #pragma unroll
        for (int q = 0; q < 8; ++q) kk[q] = kv[q * 512];
        #pragma unroll
        for (int q = 0; q < 8; ++q) {
            float cr = xr[2 * q], ci = xi[2 * q];
            xr[2 * q] = cr * kk[q].x - ci * kk[q].y;
            xi[2 * q] = cr * kk[q].y + ci * kk[q].x;
            cr = xr[2 * q + 1]; ci = xi[2 * q + 1];
            xr[2 * q + 1] = cr * kk[q].z - ci * kk[q].w;
            xi[2 * q + 1] = cr * kk[q].w + ci * kk[q].z;
        }
    }
    inv_fft(xr, xi, fre, fim, t);

    // ---- redistribute y (A -> 8-contig), epilogue fully in 8-contig, u16x8 stores ----
    __syncthreads();                 // protect inv_fft's last xchg reads
    #pragma unroll
    for (int s = 0; s < 8; ++s) {
        fre[PIDX(t + (s << 9))] = xr[s];
        fim[PIDX(t + (s << 9))] = xi[s];
    }
    __syncthreads();
    float yr[8], yi[8];
    #pragma unroll
    for (int q = 0; q < 2; ++q) {
        f32x4 vr = *(const f32x4*)&fre[PIDX(lb + 4*q)];
        f32x4 vi = *(const f32x4*)&fim[PIDX(lb + 4*q)];
        yr[4*q+0] = vr.x; yr[4*q+1] = vr.y; yr[4*q+2] = vr.z; yr[4*q+3] = vr.w;
        yi[4*q+0] = vi.x; yi[4*q+1] = vi.y; yi[4*q+2] = vi.z; yi[4*q+3] = vi.w;
    }
    const float inv_n = 1.0f / 8192.0f;
    u16x8 z0v, z1v;
    #pragma unroll
    for (int j = 0; j < 8; ++j) {
        z0v[j] = (unsigned short)f2b((yr[j] * inv_n + vgc[0][j] * fb) * x0c[0][j]);
        z1v[j] = (unsigned short)f2b((yi[j] * inv_n + vgc[1][j] * fb) * x0c[1][j]);
    }
    *(u16x8*)&zb[(size_t)d * 4096 + lb]          = z0v;
    *(u16x8*)&zb[(size_t)(2048 + d) * 4096 + lb] = z1v;
}

// ---------- (B,D,L) bf16 -> (B,L,D) bf16 transpose ----------
__global__ __launch_bounds__(256) void transpose_kernel(const unsigned short* __restrict__ zb,
                                                        unsigned short* __restrict__ zt)
{
    __shared__ unsigned int tile[64][65];
    const int l0 = blockIdx.x * 64, d0 = blockIdx.y * 64, b = blockIdx.z;
    const int tid = threadIdx.x;
    for (int e = tid; e < 4096; e += 256) {
        const int r = e >> 6, c = e & 63;  // r = d-local, c = l-local
        tile[r][c] = zb[(size_t)(b * 2048 + d0 + r) * 4096 + l0 + c];
    }
    __syncthreads();
    for (int e = tid; e < 4096; e += 256) {
        const int r = e >> 6, c = e & 63;  // r = l-local, c = d-local
        zt[(size_t)(b * 4096 + l0 + r) * 2048 + d0 + c] = (unsigned short)tile[c][r];
    }
}

// ---------- launch ----------
// Workspace lifetime plan (256 MiB total), regions:
//   B: [0, 128 MiB)       xb(32)+wbi(24) -> kspec(128) -> ztb(32)+wbo(8)
//   A: [128, 224 MiB)     ub (96 MiB, gemm1-out .. hyena-in)
//   C: [224, 256 MiB)     kf (32 MiB, filter-out .. kfft-in) -> zbm (32 MiB)
extern "C" void kernel_launch(void* const* d_in, const int* in_sizes, int n_in,
                              void* d_out, int out_size, void* d_ws, size_t ws_size,
                              hipStream_t stream)
{
    const float* x   = (const float*)d_in[0];
    const float* ipw = (const float*)d_in[1];
    const float* ipb = (const float*)d_in[2];
    const float* sw  = (const float*)d_in[3];
    const float* sb  = (const float*)d_in[4];
    const float* w0  = (const float*)d_in[5];
    const float* b0  = (const float*)d_in[6];
    const float* fr  = (const float*)d_in[7];
    const float* w1  = (const float*)d_in[8];
    const float* b1  = (const float*)d_in[9];
    const float* w2  = (const float*)d_in[10];
    const float* b2  = (const float*)d_in[11];
    const float* w3  = (const float*)d_in[12];
    const float* fb  = (const float*)d_in[13];
    const float* opw = (const float*)d_in[14];
    const float* opb = (const float*)d_in[15];
    float* out = (float*)d_out;

    char* ws = (char*)d_ws;
    // region B (reused three times)
    unsigned short* xb    = (unsigned short*)ws;                 // 32 MiB
    unsigned short* wbi   = (unsigned short*)(ws + 33554432);    // 24 MiB
    float*          kspec = (float*)ws;                          // 128 MiB (after gemm1)
    unsigned short* ztb   = (unsigned short*)ws;                 // 32 MiB (after hyena)
    unsigned short* wbo   = (unsigned short*)(ws + 33554432);    // 8 MiB (after hyena)
    // region A
    unsigned short* ub    = (unsigned short*)(ws + 134217728);   // 96 MiB
    // region C (reused twice)
    float*          kf    = (float*)(ws + 234881024);            // 32 MiB
    unsigned short* zbm   = (unsigned short*)(ws + 234881024);   // 32 MiB (after kfft)

    cvt_f32_bf16<<<1024, 256, 0, stream>>>(x,   xb,  16777216 / 4);
    cvt_f32_bf16<<<1024, 256, 0, stream>>>(ipw, wbi, 12582912 / 4);

    // u = (x @ W_in^T + b) written transposed to (B, 3D, L); frees xb/wbi afterwards
    // grid = (8192/256) * (6144/256) = 32 * 24 = 768 (1D, XCD-swizzled in-kernel)
    gemm256<1><<<768, 512, 0, stream>>>(xb, wbi, ipb, ub, 8192, 6144, 2048, 4096, 6144, 24);

    filter_kernel<<<dim3(64, 8), 256, 0, stream>>>(w0, b0, fr, w1, b1, w2, b2, w3, kf);

    // K spectrum precompute (overwrites xb/wbi region)
    kfft_kernel<<<2048, 512, 0, stream>>>(kf, kspec);

    // fused conv+gate+fftconv (overwrites kf region with zbm)
    hyena_fft_kernel<<<2048, 512, 0, stream>>>(ub, kspec, sw, sb, fb, zbm);

    transpose_kernel<<<dim3(64, 32, 2), 256, 0, stream>>>(zbm, ztb);

    // out-proj weight convert after kspec is dead (its region overlaps)
    cvt_f32_bf16<<<512,  256, 0, stream>>>(opw, wbo, 4194304 / 4);

    // out = z @ W_out^T + b (f32); grid = 32 * 8 = 256
    gemm256<0><<<256, 512, 0, stream>>>(ztb, wbo, opb, out, 8192, 2048, 2048, 4096, 2048, 8);
}

// Round 5
// 733.326 us; speedup vs baseline: 1.2887x; 1.0225x over previous
//
#include <hip/hip_runtime.h>
#include <hip/hip_bf16.h>
#include <cstdint>
#include <cstddef>

// ---------- types ----------
typedef __attribute__((ext_vector_type(8))) short    bf16x8;   // 8 bf16 = 4 VGPRs (MFMA A/B frag)
typedef __attribute__((ext_vector_type(4))) float    f32x4;    // MFMA C/D frag
typedef __attribute__((ext_vector_type(8))) unsigned short u16x8;
typedef __attribute__((ext_vector_type(4))) float    f32v4;
typedef __attribute__((ext_vector_type(4))) unsigned short u16v4;

__device__ __forceinline__ float b2f(unsigned short v) {
    return __builtin_bit_cast(float, ((unsigned int)v) << 16);
}
__device__ __forceinline__ unsigned short f2b(float f) {
    unsigned int u = __builtin_bit_cast(unsigned int, f);
    u += 0x7fffu + ((u >> 16) & 1u);        // RNE
    return (unsigned short)(u >> 16);
}

__device__ __forceinline__ void async16(const void* g, void* l) {
    __builtin_amdgcn_global_load_lds(
        (const __attribute__((address_space(1))) unsigned int*)g,
        (__attribute__((address_space(3))) unsigned int*)l, 16, 0, 0);
}

// ---------- f32 -> bf16 convert (two buffers in one dispatch) ----------
__global__ __launch_bounds__(256) void cvt2_f32_bf16(
    const float* __restrict__ srcA, unsigned short* __restrict__ dstA, int n4A,
    const float* __restrict__ srcB, unsigned short* __restrict__ dstB, int n4B) {
    int i = blockIdx.x * blockDim.x + threadIdx.x;
    int stride = gridDim.x * blockDim.x;
    const int nTot = n4A + n4B;
    for (; i < nTot; i += stride) {
        const bool inA = (i < n4A);
        const f32v4* s4 = inA ? (const f32v4*)srcA : (const f32v4*)srcB;
        u16v4* d4 = inA ? (u16v4*)dstA : (u16v4*)dstB;
        const int k = inA ? i : (i - n4A);
        f32v4 v = s4[k];
        u16v4 o;
        o.x = f2b(v.x); o.y = f2b(v.y); o.z = f2b(v.z); o.w = f2b(v.w);
        d4[k] = o;
    }
}

__global__ __launch_bounds__(256) void cvt_f32_bf16(const float* __restrict__ src,
                                                    unsigned short* __restrict__ dst, int n4) {
    int i = blockIdx.x * blockDim.x + threadIdx.x;
    int stride = gridDim.x * blockDim.x;
    const f32v4* s4 = (const f32v4*)src;
    u16v4* d4 = (u16v4*)dst;
    for (; i < n4; i += stride) {
        f32v4 v = s4[i];
        u16v4 o;
        o.x = f2b(v.x); o.y = f2b(v.y); o.z = f2b(v.z); o.w = f2b(v.w);
        d4[i] = o;
    }
}

// ============ 256x256-tile 8-phase bf16 MFMA GEMM (m201-style schedule) ============
// C[m][n] = sum_k A[m][k]*Bw[n][k] + bias[n]
// 512 threads = 8 waves (2 M x 4 N); per-wave C = 128x64 = acc[8][4] f32x4.
// BK=64; LDS double-buffered by K-tile parity: buf b at b*65536: A 32KB @0, B 32KB @32768.
// A LDS row order permutes 64-row blocks {0,2,1,3} so half h0 = rows read by quads 0-1.
// XOR swizzle: LDS[L][u] holds global unit u^(L&7) (pre-swizzled global source, linear dest).
// Block->tile map (r4): XCD x = bid&7 owns by-stripe [4x,4x+4); within-stripe order gives
// 8bx x 4by supertiles so the ~32 concurrent blocks/XCD share an 8 MiB B + 4 MiB A working
// set (halves L2-miss refetch vs row-major chunks). Requires nby==32, ntn in {8,16,24}.
// Schedule per iteration (2 K-tiles t0=2i buf0, t1=2i+1 buf1), 8 phases:
//   P1: LDB(0)+LDA(0,q0) | stage A(t1)h1            P5: LDB(1)+LDA(1,q0) | stage A(t0+2)h1
//   P2: LDA(0,q1)        | stage B(t0+2)h0          P6: LDA(1,q1)        | stage B(t1+2)h0
//   P3: LDA(0,q2)        | stage B(t0+2)h1          P7: LDA(1,q2)        | stage B(t1+2)h1
//   P4: LDA(0,q3)        | stage A(t0+2)h0 +vmcnt6  P8: LDA(1,q3)        | stage A(t1+2)h0 +vmcnt6
// vmcnt(6) at P4 drains through P1's loads, at P8 drains through P5's. Last iter: vmcnt(0).
// MODE 0: Cout = float row-major [M][N].  MODE 1: bf16 u-layout Cout[(bI*CH+n)*Lseq+l].
template <int MODE>
__global__ __launch_bounds__(512, 1) void gemm256(
    const unsigned short* __restrict__ A,   // M x K bf16 row-major
    const unsigned short* __restrict__ Bw,  // N x K bf16 row-major
    const float* __restrict__ bias,         // N
    void* __restrict__ Cout,
    int M, int N, int K, int Lseq, int CH, int ntn)
{
    constexpr int SMEM_BYTES = (MODE == 1) ? 135168 : 131072;   // epi needs 256*264*2
    __shared__ char smemc[SMEM_BYTES];

    const int tid = threadIdx.x;
    const int w   = tid >> 6;           // wave 0..7
    const int l   = tid & 63;
    const int wm  = w & 1;              // 2 waves in M
    const int wn  = w >> 1;             // 4 waves in N
    const int quad = l >> 4;
    const int lq   = l & 15;

    // XCD supertile remap (bijective: bid <-> (x, j&7, (j>>3)&3, j>>5))
    const int bid = blockIdx.x;
    const int x  = bid & 7;
    const int j  = bid >> 3;
    const int bx = (j & 7) + 8 * (j >> 5);
    const int by = (x << 2) | ((j >> 3) & 3);
    const int n0 = bx * 256, m0 = by * 256;

    // swizzled ds_read unit indices (global k-unit kk*4+quad lives at LDS unit ^ (row&7))
    const int su0 = quad ^ (lq & 7);
    const int su1 = su0 ^ 4;

    // staging: per wave 2 insts per (operand, half); lane fetches pre-swizzled global unit
    uint32_t offAe[2][2], offBe[2][2];
    int dA[2][2], dB[2][2];
    #pragma unroll
    for (int h = 0; h < 2; ++h)
        #pragma unroll
        for (int c = 0; c < 2; ++c) {
            const int Lr = h * 128 + w * 16 + c * 8 + (l >> 3);
            const int gA = ((Lr & 64) << 1) | ((Lr & 128) >> 1) | (Lr & 63);  // block perm {0,2,1,3}
            const int u  = (l & 7) ^ (l >> 3);
            offAe[h][c] = (uint32_t)(m0 + gA) * (uint32_t)K + (uint32_t)(u * 8);
            offBe[h][c] = (uint32_t)(n0 + Lr) * (uint32_t)K + (uint32_t)(u * 8);
            const int rb = (h * 128 + w * 16 + c * 8) * 128;   // LDS byte row base (wave-uniform)
            dA[h][c] = rb;
            dB[h][c] = 32768 + rb;
        }

#define STAGE_A(bs, h, tile) do { \
    async16(A + offAe[h][0] + (size_t)(tile) * 64, smemc + ((bs) * 65536 + dA[h][0])); \
    async16(A + offAe[h][1] + (size_t)(tile) * 64, smemc + ((bs) * 65536 + dA[h][1])); \
} while (0)
#define STAGE_B(bs, h, tile) do { \
    async16(Bw + offBe[h][0] + (size_t)(tile) * 64, smemc + ((bs) * 65536 + dB[h][0])); \
    async16(Bw + offBe[h][1] + (size_t)(tile) * 64, smemc + ((bs) * 65536 + dB[h][1])); \
} while (0)

    f32x4 acc[8][4] = {};
    bf16x8 bw[4][2], a[2][2];

#define LDB8(bs) do { \
    _Pragma("unroll") for (int jj = 0; jj < 4; ++jj) { \
        const int Lr = wn * 64 + jj * 16 + lq; \
        bw[jj][0] = *(const bf16x8*)(smemc + (bs) * 65536 + 32768 + Lr * 128 + su0 * 16); \
        bw[jj][1] = *(const bf16x8*)(smemc + (bs) * 65536 + 32768 + Lr * 128 + su1 * 16); \
    } } while (0)
#define LDA4(bs, q) do { \
    _Pragma("unroll") for (int mf = 0; mf < 2; ++mf) { \
        const int g = wm * 128 + (q) * 32 + mf * 16 + lq; \
        const int Lr = ((g & 64) << 1) | ((g & 128) >> 1) | (g & 63); \
        a[mf][0] = *(const bf16x8*)(smemc + (bs) * 65536 + Lr * 128 + su0 * 16); \
        a[mf][1] = *(const bf16x8*)(smemc + (bs) * 65536 + Lr * 128 + su1 * 16); \
    } } while (0)
#define MFMA16(q) do { \
    _Pragma("unroll") for (int mf = 0; mf < 2; ++mf) \
    _Pragma("unroll") for (int jj = 0; jj < 4; ++jj) \
    _Pragma("unroll") for (int kk = 0; kk < 2; ++kk) \
        acc[(q) * 2 + mf][jj] = __builtin_amdgcn_mfma_f32_16x16x32_bf16(a[mf][kk], bw[jj][kk], acc[(q) * 2 + mf][jj], 0, 0, 0); \
} while (0)
#define PHASE_SYNC() do { \
    __builtin_amdgcn_s_barrier(); \
    asm volatile("s_waitcnt lgkmcnt(0)" ::: "memory"); \
    __builtin_amdgcn_sched_barrier(0); \
    __builtin_amdgcn_s_setprio(1); \
} while (0)
#define PHASE_END() do { \
    __builtin_amdgcn_s_setprio(0); \
    __builtin_amdgcn_s_barrier(); \
} while (0)
#define PHASE_END_DRAIN(lastf) do { \
    __builtin_amdgcn_s_setprio(0); \
    if (lastf) asm volatile("s_waitcnt vmcnt(0)" ::: "memory"); \
    else       asm volatile("s_waitcnt vmcnt(6)" ::: "memory"); \
    __builtin_amdgcn_s_barrier(); \
} while (0)

    // prologue: tile0 full + tile1 all-but-Ah1 (14 loads/wave); drain tile0, keep 6 in flight
    STAGE_B(0, 0, 0); STAGE_B(0, 1, 0); STAGE_A(0, 0, 0); STAGE_A(0, 1, 0);
    STAGE_B(1, 0, 1); STAGE_B(1, 1, 1); STAGE_A(1, 0, 1);
    asm volatile("s_waitcnt vmcnt(6)" ::: "memory");
    __builtin_amdgcn_s_barrier();

    const int nIt = K >> 7;             // 2 K-tiles (BK=64) per iteration
    for (int i = 0; i < nIt; ++i) {
        const bool last = (i == nIt - 1);
        const int t0 = 2 * i, t1 = 2 * i + 1;
        // P1
        LDB8(0); LDA4(0, 0); STAGE_A(1, 1, t1);
        PHASE_SYNC(); MFMA16(0); PHASE_END();
        // P2
        LDA4(0, 1); if (!last) STAGE_B(0, 0, t0 + 2);
        PHASE_SYNC(); MFMA16(1); PHASE_END();
        // P3
        LDA4(0, 2); if (!last) STAGE_B(0, 1, t0 + 2);
        PHASE_SYNC(); MFMA16(2); PHASE_END();
        // P4
        LDA4(0, 3); if (!last) STAGE_A(0, 0, t0 + 2);
        PHASE_SYNC(); MFMA16(3); PHASE_END_DRAIN(last);
        // P5
        LDB8(1); LDA4(1, 0); if (!last) STAGE_A(0, 1, t0 + 2);
        PHASE_SYNC(); MFMA16(0); PHASE_END();
        // P6
        LDA4(1, 1); if (!last) STAGE_B(1, 0, t1 + 2);
        PHASE_SYNC(); MFMA16(1); PHASE_END();
        // P7
        LDA4(1, 2); if (!last) STAGE_B(1, 1, t1 + 2);
        PHASE_SYNC(); MFMA16(2); PHASE_END();
        // P8
        LDA4(1, 3); if (!last) STAGE_A(1, 0, t1 + 2);
        PHASE_SYNC(); MFMA16(3); PHASE_END_DRAIN(last);
    }

    if (MODE == 0) {
        float* out = (float*)Cout;
        #pragma unroll
        for (int jj = 0; jj < 4; ++jj) {
            const int col = n0 + wn * 64 + jj * 16 + lq;
            const float bv = bias[col];
            #pragma unroll
            for (int i8 = 0; i8 < 8; ++i8) {
                const int rowb = m0 + wm * 128 + i8 * 16 + quad * 4;
                f32x4 c = acc[i8][jj];
                out[(size_t)(rowb + 0) * N + col] = c.x + bv;
                out[(size_t)(rowb + 1) * N + col] = c.y + bv;
                out[(size_t)(rowb + 2) * N + col] = c.z + bv;
                out[(size_t)(rowb + 3) * N + col] = c.w + bv;
            }
        }
    } else {
        // transpose through LDS (alias staging buffers; loop fully drained at last PHASE_END_DRAIN)
        unsigned short* sE = (unsigned short*)smemc;   // [256][264]
        __syncthreads();
        #pragma unroll
        for (int jj = 0; jj < 4; ++jj) {
            const int nl = wn * 64 + jj * 16 + lq;
            const float bv = bias[n0 + nl];
            #pragma unroll
            for (int i8 = 0; i8 < 8; ++i8) {
                const int ml = wm * 128 + i8 * 16 + quad * 4;
                f32x4 c = acc[i8][jj];
                u16v4 pk;
                pk.x = f2b(c.x + bv); pk.y = f2b(c.y + bv);
                pk.z = f2b(c.z + bv); pk.w = f2b(c.w + bv);
                *(u16v4*)&sE[nl * 264 + ml] = pk;
            }
        }
        __syncthreads();
        unsigned short* uo = (unsigned short*)Cout;
        const int bI = m0 >> 12;        // 4096 rows per batch (M-tiles never straddle)
        const int l0 = m0 & 4095;
        for (int e = tid; e < 8192; e += 512) {
            const int nl = e >> 5, seg = e & 31;
            u16x8 v = *(const u16x8*)&sE[nl * 264 + seg * 8];
            *(u16x8*)&uo[(size_t)(bI * CH + n0 + nl) * Lseq + l0 + seg * 8] = v;
        }
    }
#undef STAGE_A
#undef STAGE_B
#undef LDB8
#undef LDA4
#undef MFMA16
#undef PHASE_SYNC
#undef PHASE_END
#undef PHASE_END_DRAIN
}

// ---------- Hyena filter k(D,L) ----------
__global__ __launch_bounds__(256) void filter_kernel(
    const float* __restrict__ w0, const float* __restrict__ b0,
    const float* __restrict__ freq,
    const float* __restrict__ w1, const float* __restrict__ b1,
    const float* __restrict__ w2, const float* __restrict__ b2,
    const float* __restrict__ w3, float* __restrict__ kf)
{
    __shared__ float ha[64][64];
    __shared__ float hb[64][64];
    const int tid = threadIdx.x;
    const int l0 = blockIdx.x * 64;
    const int d0 = blockIdx.y * 256;
    const int l  = tid & 63;
    const int lg = l0 + l;
    const float tt = (float)lg * (1.0f / 4095.0f);
    const float wang = 6.283185307179586f * (float)lg * (1.0f / 4096.0f);
    const float a  = 1e-4f * wang;
    const float z0 = tt, z1 = cosf(a), z2 = -sinf(a);

    for (int e = tid; e < 4096; e += 256) {
        const int dim = e >> 6;
        float pre = z0 * w0[dim * 3] + z1 * w0[dim * 3 + 1] + z2 * w0[dim * 3 + 2] + b0[dim];
        ha[dim][l] = sinf(freq[dim] * pre);
    }
    __syncthreads();
    for (int e = tid; e < 4096; e += 256) {
        const int dim = e >> 6;
        float acc = b1[dim];
        #pragma unroll
        for (int jj = 0; jj < 64; ++jj) acc += w1[dim * 64 + jj] * ha[jj][l];
        hb[dim][l] = sinf(freq[dim] * acc);
    }
    __syncthreads();
    for (int e = tid; e < 4096; e += 256) {
        const int dim = e >> 6;
        float acc = b2[dim];
        #pragma unroll
        for (int jj = 0; jj < 64; ++jj) acc += w2[dim * 64 + jj] * hb[jj][l];
        ha[dim][l] = sinf(freq[dim] * acc);
    }
    __syncthreads();
    for (int d = d0 + (tid >> 6); d < d0 + 256; d += 4) {
        float acc = 0.f;
        #pragma unroll
        for (int jj = 0; jj < 64; ++jj) acc += w3[d * 64 + jj] * ha[jj][l];
        // deltas = linspace(ln(.01)/1.5, ln(.01)/0.3, 2048); decay = exp(-t*|delta|)
        const float delta = fabsf(-3.0701134573253944f + (-5.999245642062483e-3f) * (float)d);
        kf[(size_t)d * 4096 + lg] = acc * __expf(-tt * delta);
    }
}

// ================= register-resident 8192-pt FFT (512 thr, 16 pts/thr) =================
// Ownerships: A: p = t + 512 s | B: p = (t>>5)*512 + (t&31) + 32 s | C: p = 16 t + j
// DIF forward ends bit-reversed-contiguous (C); inverse DIT consumes C and ends at A.
// LDS pad: +4 floats per 32 (PIDX) -> preserves 16B alignment of 8/16-aligned runs, so the
// C-side xchg and 8-contig conv I/O use ds_{read,write}_b128; all patterns stay <=2-way banked.
#define PIDX(i) ((i) + (((i) >> 5) << 2))

__device__ __forceinline__ void bfly_f(float& r1, float& i1, float& r2, float& i2, float wr, float wi) {
    float ur = r1, ui = i1, vr = r2, vi = i2;
    r1 = ur + vr; i1 = ui + vi;
    float dr = ur - vr, di = ui - vi;
    r2 = dr * wr - di * wi;
    i2 = dr * wi + di * wr;
}
__device__ __forceinline__ void bfly_i(float& r1, float& i1, float& r2, float& i2, float wr, float wi) {
    float vr = r2 * wr - i2 * wi, vi = r2 * wi + i2 * wr;
    float ur = r1, ui = i1;
    r1 = ur + vr; i1 = ui + vi;
    r2 = ur - vr; i2 = ui - vi;
}

// stage hm = STR*DS; j = tt + STR*(s mod DS); theta = -pi*j/hm (fwd) / +pi*j/hm (inv)
template <int DS, int STR>
__device__ __forceinline__ void fwd_stage(float* re, float* im, int tt) {
    float wr[8], wi[8];
    constexpr float c = -3.14159265358979f / (float)(STR * DS);
    #pragma unroll
    for (int k = 0; k < DS; ++k) __sincosf(c * (float)(tt + STR * k), &wi[k], &wr[k]);
    #pragma unroll
    for (int s = 0; s < 16; ++s)
        if ((s & DS) == 0)
            bfly_f(re[s], im[s], re[s + DS], im[s + DS], wr[s & (DS - 1)], wi[s & (DS - 1)]);
}
template <int DS, int STR>
__device__ __forceinline__ void inv_stage(float* re, float* im, int tt) {
    float wr[8], wi[8];
    constexpr float c = 3.14159265358979f / (float)(STR * DS);
    #pragma unroll
    for (int k = 0; k < DS; ++k) __sincosf(c * (float)(tt + STR * k), &wi[k], &wr[k]);
    #pragma unroll
    for (int s = 0; s < 16; ++s)
        if ((s & DS) == 0)
            bfly_i(re[s], im[s], re[s + DS], im[s + DS], wr[s & (DS - 1)], wi[s & (DS - 1)]);
}

// STR==1 stages (tt==0): twiddles are compile-time constants cos/sin(k*pi/DS) -> literal
// table indexed at k*(8/DS); avoids ~15 runtime __sincosf per direction per thread.
__device__ constexpr float TW8C[8] = { 1.f,  0.9238795325112867f,  0.7071067811865476f,  0.3826834323650898f,
                                       0.f, -0.3826834323650898f, -0.7071067811865476f, -0.9238795325112867f };
__device__ constexpr float TW8S[8] = { 0.f,  0.3826834323650898f,  0.7071067811865476f,  0.9238795325112867f,
                                       1.f,  0.9238795325112867f,  0.7071067811865476f,  0.3826834323650898f };
template <int DS>
__device__ __forceinline__ void fwd_stageC(float* re, float* im) {
    #pragma unroll
    for (int s = 0; s < 16; ++s)
        if ((s & DS) == 0) {
            const int k = (s & (DS - 1)) * (8 / DS);
            bfly_f(re[s], im[s], re[s + DS], im[s + DS], TW8C[k], -TW8S[k]);
        }
}
template <int DS>
__device__ __forceinline__ void inv_stageC(float* re, float* im) {
    #pragma unroll
    for (int s = 0; s < 16; ++s)
        if ((s & DS) == 0) {
            const int k = (s & (DS - 1)) * (8 / DS);
            bfly_i(re[s], im[s], re[s + DS], im[s + DS], TW8C[k], TW8S[k]);
        }
}

// xchg: wstr==1 / rstr==1 (C-ownership side) vectorize to 4x b128 (16t is 16-aligned; the
// +4/32 pad keeps any 4-run inside one 32-segment contiguous and 16B-aligned).
__device__ __forceinline__ void xchg(float* re, float* im, float* fre, float* fim,
                                     int wbase, int wstr, int rbase, int rstr) {
    __syncthreads();           // protect prior reads of fre/fim
    if (wstr == 1) {
        #pragma unroll
        for (int q = 0; q < 4; ++q) {
            f32x4 vr, vi;
            vr.x = re[4*q+0]; vr.y = re[4*q+1]; vr.z = re[4*q+2]; vr.w = re[4*q+3];
            vi.x = im[4*q+0]; vi.y = im[4*q+1]; vi.z = im[4*q+2]; vi.w = im[4*q+3];
            *(f32x4*)&fre[PIDX(wbase + 4*q)] = vr;
            *(f32x4*)&fim[PIDX(wbase + 4*q)] = vi;
        }
    } else {
        #pragma unroll
        for (int s = 0; s < 16; ++s) {
            const int i = wbase + wstr * s;
            fre[PIDX(i)] = re[s]; fim[PIDX(i)] = im[s];
        }
    }
    __syncthreads();
    if (rstr == 1) {
        #pragma unroll
        for (int q = 0; q < 4; ++q) {
            f32x4 vr = *(const f32x4*)&fre[PIDX(rbase + 4*q)];
            f32x4 vi = *(const f32x4*)&fim[PIDX(rbase + 4*q)];
            re[4*q+0] = vr.x; re[4*q+1] = vr.y; re[4*q+2] = vr.z; re[4*q+3] = vr.w;
            im[4*q+0] = vi.x; im[4*q+1] = vi.y; im[4*q+2] = vi.z; im[4*q+3] = vi.w;
        }
    } else {
        #pragma unroll
        for (int s = 0; s < 16; ++s) {
            const int i = rbase + rstr * s;
            re[s] = fre[PIDX(i)]; im[s] = fim[PIDX(i)];
        }
    }
}

__device__ __forceinline__ void fwd_fft(float* re, float* im, float* fre, float* fim, int t) {
    const int off = t & 31, seg = t >> 5;
    fwd_stage<8, 512>(re, im, t);
    fwd_stage<4, 512>(re, im, t);
    fwd_stage<2, 512>(re, im, t);
    fwd_stage<1, 512>(re, im, t);
    xchg(re, im, fre, fim, t, 512, seg * 512 + off, 32);        // A -> B
    fwd_stage<8, 32>(re, im, off);
    fwd_stage<4, 32>(re, im, off);
    fwd_stage<2, 32>(re, im, off);
    fwd_stage<1, 32>(re, im, off);
    {   // hm = 16 (m = 32) across threads t ^ 16; j = off & 15 (thread-constant)
        float wr, wi;
        __sincosf(-3.14159265358979f * (float)(off & 15) / 16.0f, &wi, &wr);
        const bool hi = (off & 16) != 0;
        #pragma unroll
        for (int s = 0; s < 16; ++s) {
            float rr = __shfl_xor(re[s], 16);
            float ri = __shfl_xor(im[s], 16);
            if (!hi) { re[s] += rr; im[s] += ri; }
            else {
                float dr = rr - re[s], di = ri - im[s];
                re[s] = dr * wr - di * wi;
                im[s] = dr * wi + di * wr;
            }
        }
    }
    xchg(re, im, fre, fim, seg * 512 + off, 32, 16 * t, 1);     // B -> C
    fwd_stageC<8>(re, im);
    fwd_stageC<4>(re, im);
    fwd_stageC<2>(re, im);
    fwd_stageC<1>(re, im);
}

__device__ __forceinline__ void inv_fft(float* re, float* im, float* fre, float* fim, int t) {
    const int off = t & 31, seg = t >> 5;
    inv_stageC<1>(re, im);
    inv_stageC<2>(re, im);
    inv_stageC<4>(re, im);
    inv_stageC<8>(re, im);
    xchg(re, im, fre, fim, 16 * t, 1, seg * 512 + off, 32);     // C -> B
    {   // hm = 16 (m = 32), conj twiddle; v' = W * x[p+16]
        float wr, wi;
        __sincosf(3.14159265358979f * (float)(off & 15) / 16.0f, &wi, &wr);
        const bool hi = (off & 16) != 0;
        #pragma unroll
        for (int s = 0; s < 16; ++s) {
            float rr = __shfl_xor(re[s], 16);
            float ri = __shfl_xor(im[s], 16);
            if (!hi) {           // u = own, v' = W * recv
                float vr = rr * wr - ri * wi, vi = rr * wi + ri * wr;
                re[s] += vr; im[s] += vi;
            } else {             // u = recv, v' = W * own
                float vr = re[s] * wr - im[s] * wi, vi = re[s] * wi + im[s] * wr;
                re[s] = rr - vr; im[s] = ri - vi;
            }
        }
    }
    inv_stage<1, 32>(re, im, off);
    inv_stage<2, 32>(re, im, off);
    inv_stage<4, 32>(re, im, off);
    inv_stage<8, 32>(re, im, off);
    xchg(re, im, fre, fim, seg * 512 + off, 32, t, 512);        // B -> A
    inv_stage<1, 512>(re, im, t);
    inv_stage<2, 512>(re, im, t);
    inv_stage<4, 512>(re, im, t);
    inv_stage<8, 512>(re, im, t);
}

// ---------- K-spectrum precompute: kspec[d] = FFT_8192(zero-padded k_d) ----------
// Layout: q-major f32x4 per (d, q, t): kspec4[d*4096 + q*512 + t] = {Kr[16t+2q], Ki[16t+2q],
// Kr[16t+2q+1], Ki[16t+2q+1]} (C ownership) -> per-instruction lane-contiguous on both sides.
// NOTE launch_bounds arg2: empirically (r1) arg2=4 with 512-thr blocks capped VGPR at 64
// (CUDA blocks-per-CU semantics) and spilled the register FFT. arg2=2 -> cap 128 = 2 blocks/CU.
__global__ __launch_bounds__(512, 2) void kfft_kernel(
    const float* __restrict__ kf,   // (D, L) f32
    float* __restrict__ kspec)      // (D, 8192) complex, packed as above
{
    __shared__ __align__(16) float fre[9216];
    __shared__ __align__(16) float fim[9216];
    const int t = threadIdx.x;
    const int d = blockIdx.x;
    float kr[16], ki[16];
    #pragma unroll
    for (int s = 0; s < 16; ++s) {
        kr[s] = (s < 8) ? kf[(size_t)d * 4096 + t + 512 * s] : 0.f;
        ki[s] = 0.f;
    }
    fwd_fft(kr, ki, fre, fim, t);
    f32x4* kv = (f32x4*)kspec + (size_t)d * 4096 + t;
    #pragma unroll
    for (int q = 0; q < 8; ++q) {
        f32x4 o;
        o.x = kr[2 * q]; o.y = ki[2 * q];
        o.z = kr[2 * q + 1]; o.w = ki[2 * q + 1];
        kv[q * 512] = o;
    }
}

// causal 3-tap depthwise conv on an 8-contiguous chunk [lb, lb+8) of one channel row
__device__ __forceinline__ void conv8(const unsigned short* __restrict__ row, int lb,
                                      float W0, float W1, float W2, float BB,
                                      float* __restrict__ out) {
    u16x8 v8 = *(const u16x8*)(row + lb);
    float f[8];
    #pragma unroll
    for (int j = 0; j < 8; ++j) f[j] = b2f(v8[j]);
    const float fm1 = (lb >= 1) ? b2f(row[lb - 1]) : 0.f;
    const float fm2 = (lb >= 2) ? b2f(row[lb - 2]) : 0.f;
    out[0] = W0 * fm2 + W1 * fm1 + W2 * f[0] + BB;
    out[1] = W0 * fm1 + W1 * f[0] + W2 * f[1] + BB;
    #pragma unroll
    for (int j = 2; j < 8; ++j) out[j] = W0 * f[j - 2] + W1 * f[j - 1] + W2 * f[j] + BB;
}

// ---------- fused: short conv + gate + fftconv + bias + x0 gate -> zb (B,D,L) bf16 ----------
// Conv + epilogue run in 8-contiguous ownership (l in [8t,8t+8)) for u16x8 global I/O;
// LDS redistribution (through fre/fim) bridges to/from the FFT's A ownership.
// LDS = fre/fim only (73,728 B) -> 2 blocks/CU; K spectrum streamed from global.
__global__ __launch_bounds__(512, 2) void hyena_fft_kernel(
    const unsigned short* __restrict__ u,   // (B, 3D, L) bf16
    const float* __restrict__ kspec,        // (D, 8192) complex, q-major f32x4
    const float* __restrict__ sw,           // (3D, 1, 3)
    const float* __restrict__ sbv,          // (3D)
    const float* __restrict__ fbias,        // (D)
    unsigned short* __restrict__ zb)        // (B, D, L) bf16
{
    __shared__ __align__(16) float fre[9216];
    __shared__ __align__(16) float fim[9216];
    const int t = threadIdx.x;
    const int d = blockIdx.x;
    const int lb = t << 3;

    // ---- phase 1: short conv + gating, 8-contig ownership, vectorized loads ----
    const int c0 = d, c1 = 2048 + d, c2 = 4096 + d;
    const float w00 = sw[c0*3+0], w01 = sw[c0*3+1], w02 = sw[c0*3+2], bb0 = sbv[c0];
    const float w10 = sw[c1*3+0], w11 = sw[c1*3+1], w12 = sw[c1*3+2], bb1 = sbv[c1];
    const float w20 = sw[c2*3+0], w21 = sw[c2*3+1], w22 = sw[c2*3+2], bb2 = sbv[c2];
    const float fb = fbias[d];

    float vgc[2][8], x0c[2][8];     // stay live (8-contig) through both FFTs
    #pragma unroll
    for (int b = 0; b < 2; ++b) {
        const size_t base = (size_t)b * 6144 * 4096;
        float a_[8], e_[8], g_[8];
        conv8(u + base + (size_t)c0 * 4096, lb, w00, w01, w02, bb0, a_);
        conv8(u + base + (size_t)c1 * 4096, lb, w10, w11, w12, bb1, e_);
        conv8(u + base + (size_t)c2 * 4096, lb, w20, w21, w22, bb2, g_);
        #pragma unroll
        for (int j = 0; j < 8; ++j) { x0c[b][j] = a_[j]; vgc[b][j] = g_[j] * e_[j]; }
    }

    // ---- redistribute vg (8-contig -> A ownership) through LDS; first LDS use, no pre-barrier ----
    #pragma unroll
    for (int q = 0; q < 2; ++q) {
        f32x4 vr, vi;
        vr.x = vgc[0][4*q+0]; vr.y = vgc[0][4*q+1]; vr.z = vgc[0][4*q+2]; vr.w = vgc[0][4*q+3];
        vi.x = vgc[1][4*q+0]; vi.y = vgc[1][4*q+1]; vi.z = vgc[1][4*q+2]; vi.w = vgc[1][4*q+3];
        *(f32x4*)&fre[PIDX(lb + 4*q)] = vr;
        *(f32x4*)&fim[PIDX(lb + 4*q)] = vi;
    }
    __syncthreads();
    float xr[16], xi[16];
    #pragma unroll
    for (int s = 0; s < 8; ++s) {
        xr[s] = fre[PIDX(t + (s << 9))];
        xi[s] = fim[PIDX(t + (s << 9))];
    }
    #pragma unroll
    for (int s = 8; s < 16; ++s) { xr[s] = 0.f; xi[s] = 0.f; }

    // ---- C = FFT(vg0 + i*vg1); pointwise *K (streamed) in C ownership; inverse to A ----
    fwd_fft(xr, xi, fre, fim, t);    // leading __syncthreads protects redistribution reads
    {
        const f32x4* kv = (const f32x4*)kspec + (size_t)d * 4096 + t;
        f32x4 kk[8];
        #pragma unroll
        for (int q = 0; q < 8; ++q) kk[q] = kv[q * 512];
        #pragma unroll
        for (int q = 0; q < 8; ++q) {
            float cr = xr[2 * q], ci = xi[2 * q];
            xr[2 * q] = cr * kk[q].x - ci * kk[q].y;
            xi[2 * q] = cr * kk[q].y + ci * kk[q].x;
            cr = xr[2 * q + 1]; ci = xi[2 * q + 1];
            xr[2 * q + 1] = cr * kk[q].z - ci * kk[q].w;
            xi[2 * q + 1] = cr * kk[q].w + ci * kk[q].z;
        }
    }
    inv_fft(xr, xi, fre, fim, t);

    // ---- redistribute y (A -> 8-contig), epilogue fully in 8-contig, u16x8 stores ----
    __syncthreads();                 // protect inv_fft's last xchg reads
    #pragma unroll
    for (int s = 0; s < 8; ++s) {
        fre[PIDX(t + (s << 9))] = xr[s];
        fim[PIDX(t + (s << 9))] = xi[s];
    }
    __syncthreads();
    float yr[8], yi[8];
    #pragma unroll
    for (int q = 0; q < 2; ++q) {
        f32x4 vr = *(const f32x4*)&fre[PIDX(lb + 4*q)];
        f32x4 vi = *(const f32x4*)&fim[PIDX(lb + 4*q)];
        yr[4*q+0] = vr.x; yr[4*q+1] = vr.y; yr[4*q+2] = vr.z; yr[4*q+3] = vr.w;
        yi[4*q+0] = vi.x; yi[4*q+1] = vi.y; yi[4*q+2] = vi.z; yi[4*q+3] = vi.w;
    }
    const float inv_n = 1.0f / 8192.0f;
    u16x8 z0v, z1v;
    #pragma unroll
    for (int j = 0; j < 8; ++j) {
        z0v[j] = (unsigned short)f2b((yr[j] * inv_n + vgc[0][j] * fb) * x0c[0][j]);
        z1v[j] = (unsigned short)f2b((yi[j] * inv_n + vgc[1][j] * fb) * x0c[1][j]);
    }
    *(u16x8*)&zb[(size_t)d * 4096 + lb]          = z0v;
    *(u16x8*)&zb[(size_t)(2048 + d) * 4096 + lb] = z1v;
}

// ---------- (B,D,L) bf16 -> (B,L,D) bf16 transpose ----------
__global__ __launch_bounds__(256) void transpose_kernel(const unsigned short* __restrict__ zb,
                                                        unsigned short* __restrict__ zt)
{
    __shared__ unsigned int tile[64][65];
    const int l0 = blockIdx.x * 64, d0 = blockIdx.y * 64, b = blockIdx.z;
    const int tid = threadIdx.x;
    for (int e = tid; e < 4096; e += 256) {
        const int r = e >> 6, c = e & 63;  // r = d-local, c = l-local
        tile[r][c] = zb[(size_t)(b * 2048 + d0 + r) * 4096 + l0 + c];
    }
    __syncthreads();
    for (int e = tid; e < 4096; e += 256) {
        const int r = e >> 6, c = e & 63;  // r = l-local, c = d-local
        zt[(size_t)(b * 4096 + l0 + r) * 2048 + d0 + c] = (unsigned short)tile[c][r];
    }
}

// ---------- launch ----------
// Workspace lifetime plan (256 MiB total), regions:
//   B: [0, 128 MiB)       xb(32)+wbi(24) -> kspec(128) -> ztb(32)+wbo(8)
//   A: [128, 224 MiB)     ub (96 MiB, gemm1-out .. hyena-in)
//   C: [224, 256 MiB)     kf (32 MiB, filter-out .. kfft-in) -> zbm (32 MiB)
extern "C" void kernel_launch(void* const* d_in, const int* in_sizes, int n_in,
                              void* d_out, int out_size, void* d_ws, size_t ws_size,
                              hipStream_t stream)
{
    const float* x   = (const float*)d_in[0];
    const float* ipw = (const float*)d_in[1];
    const float* ipb = (const float*)d_in[2];
    const float* sw  = (const float*)d_in[3];
    const float* sb  = (const float*)d_in[4];
    const float* w0  = (const float*)d_in[5];
    const float* b0  = (const float*)d_in[6];
    const float* fr  = (const float*)d_in[7];
    const float* w1  = (const float*)d_in[8];
    const float* b1  = (const float*)d_in[9];
    const float* w2  = (const float*)d_in[10];
    const float* b2  = (const float*)d_in[11];
    const float* w3  = (const float*)d_in[12];
    const float* fb  = (const float*)d_in[13];
    const float* opw = (const float*)d_in[14];
    const float* opb = (const float*)d_in[15];
    float* out = (float*)d_out;

    char* ws = (char*)d_ws;
    // region B (reused three times)
    unsigned short* xb    = (unsigned short*)ws;                 // 32 MiB
    unsigned short* wbi   = (unsigned short*)(ws + 33554432);    // 24 MiB
    float*          kspec = (float*)ws;                          // 128 MiB (after gemm1)
    unsigned short* ztb   = (unsigned short*)ws;                 // 32 MiB (after hyena)
    unsigned short* wbo   = (unsigned short*)(ws + 33554432);    // 8 MiB (after hyena)
    // region A
    unsigned short* ub    = (unsigned short*)(ws + 134217728);   // 96 MiB
    // region C (reused twice)
    float*          kf    = (float*)(ws + 234881024);            // 32 MiB
    unsigned short* zbm   = (unsigned short*)(ws + 234881024);   // 32 MiB (after kfft)

    cvt2_f32_bf16<<<1536, 256, 0, stream>>>(x, xb, 16777216 / 4, ipw, wbi, 12582912 / 4);

    // u = (x @ W_in^T + b) written transposed to (B, 3D, L); frees xb/wbi afterwards
    // grid = (8192/256) * (6144/256) = 32 * 24 = 768 (1D, XCD-supertile-swizzled in-kernel)
    gemm256<1><<<768, 512, 0, stream>>>(xb, wbi, ipb, ub, 8192, 6144, 2048, 4096, 6144, 24);

    filter_kernel<<<dim3(64, 8), 256, 0, stream>>>(w0, b0, fr, w1, b1, w2, b2, w3, kf);

    // K spectrum precompute (overwrites xb/wbi region)
    kfft_kernel<<<2048, 512, 0, stream>>>(kf, kspec);

    // fused conv+gate+fftconv (overwrites kf region with zbm)
    hyena_fft_kernel<<<2048, 512, 0, stream>>>(ub, kspec, sw, sb, fb, zbm);

    transpose_kernel<<<dim3(64, 32, 2), 256, 0, stream>>>(zbm, ztb);

    // out-proj weight convert after kspec is dead (its region overlaps)
    cvt_f32_bf16<<<512,  256, 0, stream>>>(opw, wbo, 4194304 / 4);

    // out = z @ W_out^T + b (f32); grid = 32 * 8 = 256
    gemm256<0><<<256, 512, 0, stream>>>(ztb, wbo, opb, out, 8192, 2048, 2048, 4096, 2048, 8);
}